// Round 1
// baseline (1638.360 us; speedup 1.0000x reference)
//
#include <hip/hip_runtime.h>
#include <math.h>

#define NN 50000
#define NE 800000
#define DD 128
#define HH 128
#define BN_EPS 1e-3f

__device__ __forceinline__ float gelu_f(float x) {
    return 0.5f * x * (1.0f + erff(x * 0.70710678118654752f));
}

// ---------------- prep FFN: msg[n] = gelu(BN1(gelu(BN0(x)@W0+b0))@W1+b1) ----
__global__ __launch_bounds__(256)
void prep_kernel(const float* __restrict__ x,
                 const float* __restrict__ bn0_g, const float* __restrict__ bn0_b,
                 const float* __restrict__ bn0_m, const float* __restrict__ bn0_v,
                 const float* __restrict__ W0, const float* __restrict__ b0,
                 const float* __restrict__ bn1_g, const float* __restrict__ bn1_b,
                 const float* __restrict__ bn1_m, const float* __restrict__ bn1_v,
                 const float* __restrict__ W1, const float* __restrict__ b1,
                 float* __restrict__ msg)
{
    __shared__ float xs[32][DD + 1];
    __shared__ float ys[32][HH + 1];
    const int row0 = blockIdx.x * 32;
    const int tid = threadIdx.x;
    const int tx = tid & 31;   // column group: cols tx*4 .. tx*4+3
    const int ty = tid >> 5;   // row group: rows ty*4 .. ty*4+3

    // load + BN0
    for (int i = tid; i < 32 * DD; i += 256) {
        int r = i >> 7, c = i & 127;
        int row = row0 + r;
        float v = (row < NN) ? x[(long long)row * DD + c] : 0.0f;
        xs[r][c] = (v - bn0_m[c]) * rsqrtf(bn0_v[c] + BN_EPS) * bn0_g[c] + bn0_b[c];
    }
    __syncthreads();

    float acc[4][4];
#pragma unroll
    for (int r = 0; r < 4; ++r)
#pragma unroll
        for (int c = 0; c < 4; ++c) acc[r][c] = 0.0f;

    for (int k = 0; k < DD; ++k) {
        float4 w = *reinterpret_cast<const float4*>(&W0[k * HH + tx * 4]);
#pragma unroll
        for (int r = 0; r < 4; ++r) {
            float xv = xs[ty * 4 + r][k];
            acc[r][0] += xv * w.x; acc[r][1] += xv * w.y;
            acc[r][2] += xv * w.z; acc[r][3] += xv * w.w;
        }
    }

    // bias + gelu + BN1 -> ys
#pragma unroll
    for (int c = 0; c < 4; ++c) {
        int col = tx * 4 + c;
        float bias = b0[col];
        float sc = rsqrtf(bn1_v[col] + BN_EPS) * bn1_g[col];
        float mm = bn1_m[col], bb = bn1_b[col];
#pragma unroll
        for (int r = 0; r < 4; ++r) {
            float y = gelu_f(acc[r][c] + bias);
            ys[ty * 4 + r][col] = (y - mm) * sc + bb;
        }
    }
    __syncthreads();

    float acc2[4][4];
#pragma unroll
    for (int r = 0; r < 4; ++r)
#pragma unroll
        for (int c = 0; c < 4; ++c) acc2[r][c] = 0.0f;

    for (int k = 0; k < HH; ++k) {
        float4 w = *reinterpret_cast<const float4*>(&W1[k * HH + tx * 4]);
#pragma unroll
        for (int r = 0; r < 4; ++r) {
            float xv = ys[ty * 4 + r][k];
            acc2[r][0] += xv * w.x; acc2[r][1] += xv * w.y;
            acc2[r][2] += xv * w.z; acc2[r][3] += xv * w.w;
        }
    }

#pragma unroll
    for (int r = 0; r < 4; ++r) {
        int row = row0 + ty * 4 + r;
        if (row < NN) {
            float4 o;
            o.x = gelu_f(acc2[r][0] + b1[tx * 4 + 0]);
            o.y = gelu_f(acc2[r][1] + b1[tx * 4 + 1]);
            o.z = gelu_f(acc2[r][2] + b1[tx * 4 + 2]);
            o.w = gelu_f(acc2[r][3] + b1[tx * 4 + 3]);
            *reinterpret_cast<float4*>(&msg[(long long)row * HH + tx * 4]) = o;
        }
    }
}

// ---------------- edge scatter: ssum[dst] += msg[src]*w ; cnt[dst] += 1 -----
__global__ __launch_bounds__(256)
void scatter_kernel(const int* __restrict__ edges, const float* __restrict__ ew,
                    const float* __restrict__ msg,
                    float* __restrict__ ssum, float* __restrict__ cnt)
{
    long long gid = (long long)blockIdx.x * 256 + threadIdx.x;
    int e = (int)(gid >> 5);
    int q = (int)(gid & 31);
    if (e >= NE) return;
    int dst = edges[e];
    int src = edges[NE + e];
    float w = ew[e];
    float4 m = *reinterpret_cast<const float4*>(&msg[(long long)src * HH + q * 4]);
    float* p = &ssum[(long long)dst * HH + q * 4];
    atomicAdd(p + 0, m.x * w);
    atomicAdd(p + 1, m.y * w);
    atomicAdd(p + 2, m.z * w);
    atomicAdd(p + 3, m.w * w);
    if (q == 0) atomicAdd(&cnt[dst], 1.0f);
}

// ---------------- update FFN over concat(x, agg) ----------------------------
__global__ __launch_bounds__(256)
void upd_kernel(const float* __restrict__ x, const float* __restrict__ ssum,
                const float* __restrict__ cnt,
                const float* __restrict__ bn0_g, const float* __restrict__ bn0_b,
                const float* __restrict__ bn0_m, const float* __restrict__ bn0_v,
                const float* __restrict__ W0, const float* __restrict__ b0,
                const float* __restrict__ bn1_g, const float* __restrict__ bn1_b,
                const float* __restrict__ bn1_m, const float* __restrict__ bn1_v,
                const float* __restrict__ W1, const float* __restrict__ b1,
                float* __restrict__ out)
{
    const int K = DD + HH; // 256
    __shared__ float xs[32][256 + 1];
    __shared__ float ys[32][HH + 1];
    const int row0 = blockIdx.x * 32;
    const int tid = threadIdx.x;
    const int tx = tid & 31;
    const int ty = tid >> 5;

    for (int i = tid; i < 32 * 256; i += 256) {
        int r = i >> 8, c = i & 255;
        int row = row0 + r;
        float v = 0.0f;
        if (row < NN) {
            if (c < DD) {
                v = x[(long long)row * DD + c];
            } else {
                float ct = cnt[row];
                float s = ssum[(long long)row * HH + (c - DD)];
                v = (ct > 0.0f) ? s / ct : 0.0f;
            }
        }
        xs[r][c] = (v - bn0_m[c]) * rsqrtf(bn0_v[c] + BN_EPS) * bn0_g[c] + bn0_b[c];
    }
    __syncthreads();

    float acc[4][4];
#pragma unroll
    for (int r = 0; r < 4; ++r)
#pragma unroll
        for (int c = 0; c < 4; ++c) acc[r][c] = 0.0f;

    for (int k = 0; k < K; ++k) {
        float4 w = *reinterpret_cast<const float4*>(&W0[k * HH + tx * 4]);
#pragma unroll
        for (int r = 0; r < 4; ++r) {
            float xv = xs[ty * 4 + r][k];
            acc[r][0] += xv * w.x; acc[r][1] += xv * w.y;
            acc[r][2] += xv * w.z; acc[r][3] += xv * w.w;
        }
    }

#pragma unroll
    for (int c = 0; c < 4; ++c) {
        int col = tx * 4 + c;
        float bias = b0[col];
        float sc = rsqrtf(bn1_v[col] + BN_EPS) * bn1_g[col];
        float mm = bn1_m[col], bb = bn1_b[col];
#pragma unroll
        for (int r = 0; r < 4; ++r) {
            float y = gelu_f(acc[r][c] + bias);
            ys[ty * 4 + r][col] = (y - mm) * sc + bb;
        }
    }
    __syncthreads();

    float acc2[4][4];
#pragma unroll
    for (int r = 0; r < 4; ++r)
#pragma unroll
        for (int c = 0; c < 4; ++c) acc2[r][c] = 0.0f;

    for (int k = 0; k < HH; ++k) {
        float4 w = *reinterpret_cast<const float4*>(&W1[k * HH + tx * 4]);
#pragma unroll
        for (int r = 0; r < 4; ++r) {
            float xv = ys[ty * 4 + r][k];
            acc2[r][0] += xv * w.x; acc2[r][1] += xv * w.y;
            acc2[r][2] += xv * w.z; acc2[r][3] += xv * w.w;
        }
    }

#pragma unroll
    for (int r = 0; r < 4; ++r) {
        int row = row0 + ty * 4 + r;
        if (row < NN) {
            float4 o;
            o.x = gelu_f(acc2[r][0] + b1[tx * 4 + 0]);
            o.y = gelu_f(acc2[r][1] + b1[tx * 4 + 1]);
            o.z = gelu_f(acc2[r][2] + b1[tx * 4 + 2]);
            o.w = gelu_f(acc2[r][3] + b1[tx * 4 + 3]);
            *reinterpret_cast<float4*>(&out[(long long)row * HH + tx * 4]) = o;
        }
    }
}

extern "C" void kernel_launch(void* const* d_in, const int* in_sizes, int n_in,
                              void* d_out, int out_size, void* d_ws, size_t ws_size,
                              hipStream_t stream) {
    const float* node_repr = (const float*)d_in[0];
    const int*   edges     = (const int*)d_in[1];
    const float* ew        = (const float*)d_in[2];

    const float* prep_bn0_g = (const float*)d_in[3];
    const float* prep_bn0_b = (const float*)d_in[4];
    const float* prep_bn0_m = (const float*)d_in[5];
    const float* prep_bn0_v = (const float*)d_in[6];
    const float* prep_W0    = (const float*)d_in[7];
    const float* prep_b0    = (const float*)d_in[8];
    const float* prep_bn1_g = (const float*)d_in[9];
    const float* prep_bn1_b = (const float*)d_in[10];
    const float* prep_bn1_m = (const float*)d_in[11];
    const float* prep_bn1_v = (const float*)d_in[12];
    const float* prep_W1    = (const float*)d_in[13];
    const float* prep_b1    = (const float*)d_in[14];

    const float* upd_bn0_g = (const float*)d_in[15];
    const float* upd_bn0_b = (const float*)d_in[16];
    const float* upd_bn0_m = (const float*)d_in[17];
    const float* upd_bn0_v = (const float*)d_in[18];
    const float* upd_W0    = (const float*)d_in[19];
    const float* upd_b0    = (const float*)d_in[20];
    const float* upd_bn1_g = (const float*)d_in[21];
    const float* upd_bn1_b = (const float*)d_in[22];
    const float* upd_bn1_m = (const float*)d_in[23];
    const float* upd_bn1_v = (const float*)d_in[24];
    const float* upd_W1    = (const float*)d_in[25];
    const float* upd_b1    = (const float*)d_in[26];

    float* ws   = (float*)d_ws;
    float* msg  = ws;                         // NN*HH
    float* ssum = ws + (size_t)NN * HH;       // NN*HH
    float* cnt  = ssum + (size_t)NN * HH;     // NN

    hipMemsetAsync(ssum, 0, (size_t)NN * HH * sizeof(float), stream);
    hipMemsetAsync(cnt, 0, (size_t)NN * sizeof(float), stream);

    int nblk = (NN + 31) / 32;
    prep_kernel<<<nblk, 256, 0, stream>>>(node_repr,
        prep_bn0_g, prep_bn0_b, prep_bn0_m, prep_bn0_v, prep_W0, prep_b0,
        prep_bn1_g, prep_bn1_b, prep_bn1_m, prep_bn1_v, prep_W1, prep_b1, msg);

    long long tot = (long long)NE * 32;
    int sblk = (int)((tot + 255) / 256);
    scatter_kernel<<<sblk, 256, 0, stream>>>(edges, ew, msg, ssum, cnt);

    upd_kernel<<<nblk, 256, 0, stream>>>(node_repr, ssum, cnt,
        upd_bn0_g, upd_bn0_b, upd_bn0_m, upd_bn0_v, upd_W0, upd_b0,
        upd_bn1_g, upd_bn1_b, upd_bn1_m, upd_bn1_v, upd_W1, upd_b1,
        (float*)d_out);
}

// Round 2
// 496.021 us; speedup vs baseline: 3.3030x; 3.3030x over previous
//
#include <hip/hip_runtime.h>
#include <math.h>

#define NN 50000
#define NE 800000
#define DD 128
#define HH 128
#define BN_EPS 1e-3f

__device__ __forceinline__ float gelu_f(float x) {
    return 0.5f * x * (1.0f + erff(x * 0.70710678118654752f));
}

// ---------------- prep FFN: msg[n] = gelu(BN1(gelu(BN0(x)@W0+b0))@W1+b1) ----
__global__ __launch_bounds__(256)
void prep_kernel(const float* __restrict__ x,
                 const float* __restrict__ bn0_g, const float* __restrict__ bn0_b,
                 const float* __restrict__ bn0_m, const float* __restrict__ bn0_v,
                 const float* __restrict__ W0, const float* __restrict__ b0,
                 const float* __restrict__ bn1_g, const float* __restrict__ bn1_b,
                 const float* __restrict__ bn1_m, const float* __restrict__ bn1_v,
                 const float* __restrict__ W1, const float* __restrict__ b1,
                 float* __restrict__ msg)
{
    __shared__ float xs[32][DD + 1];
    __shared__ float ys[32][HH + 1];
    const int row0 = blockIdx.x * 32;
    const int tid = threadIdx.x;
    const int tx = tid & 31;   // column group: cols tx*4 .. tx*4+3
    const int ty = tid >> 5;   // row group: rows ty*4 .. ty*4+3

    // load + BN0
    for (int i = tid; i < 32 * DD; i += 256) {
        int r = i >> 7, c = i & 127;
        int row = row0 + r;
        float v = (row < NN) ? x[(long long)row * DD + c] : 0.0f;
        xs[r][c] = (v - bn0_m[c]) * rsqrtf(bn0_v[c] + BN_EPS) * bn0_g[c] + bn0_b[c];
    }
    __syncthreads();

    float acc[4][4];
#pragma unroll
    for (int r = 0; r < 4; ++r)
#pragma unroll
        for (int c = 0; c < 4; ++c) acc[r][c] = 0.0f;

    for (int k = 0; k < DD; ++k) {
        float4 w = *reinterpret_cast<const float4*>(&W0[k * HH + tx * 4]);
#pragma unroll
        for (int r = 0; r < 4; ++r) {
            float xv = xs[ty * 4 + r][k];
            acc[r][0] += xv * w.x; acc[r][1] += xv * w.y;
            acc[r][2] += xv * w.z; acc[r][3] += xv * w.w;
        }
    }

    // bias + gelu + BN1 -> ys
#pragma unroll
    for (int c = 0; c < 4; ++c) {
        int col = tx * 4 + c;
        float bias = b0[col];
        float sc = rsqrtf(bn1_v[col] + BN_EPS) * bn1_g[col];
        float mm = bn1_m[col], bb = bn1_b[col];
#pragma unroll
        for (int r = 0; r < 4; ++r) {
            float y = gelu_f(acc[r][c] + bias);
            ys[ty * 4 + r][col] = (y - mm) * sc + bb;
        }
    }
    __syncthreads();

    float acc2[4][4];
#pragma unroll
    for (int r = 0; r < 4; ++r)
#pragma unroll
        for (int c = 0; c < 4; ++c) acc2[r][c] = 0.0f;

    for (int k = 0; k < HH; ++k) {
        float4 w = *reinterpret_cast<const float4*>(&W1[k * HH + tx * 4]);
#pragma unroll
        for (int r = 0; r < 4; ++r) {
            float xv = ys[ty * 4 + r][k];
            acc2[r][0] += xv * w.x; acc2[r][1] += xv * w.y;
            acc2[r][2] += xv * w.z; acc2[r][3] += xv * w.w;
        }
    }

#pragma unroll
    for (int r = 0; r < 4; ++r) {
        int row = row0 + ty * 4 + r;
        if (row < NN) {
            float4 o;
            o.x = gelu_f(acc2[r][0] + b1[tx * 4 + 0]);
            o.y = gelu_f(acc2[r][1] + b1[tx * 4 + 1]);
            o.z = gelu_f(acc2[r][2] + b1[tx * 4 + 2]);
            o.w = gelu_f(acc2[r][3] + b1[tx * 4 + 3]);
            *reinterpret_cast<float4*>(&msg[(long long)row * HH + tx * 4]) = o;
        }
    }
}

// ---------------- CSR build ------------------------------------------------
__global__ __launch_bounds__(256)
void degree_kernel(const int* __restrict__ edges, int* __restrict__ deg)
{
    int e = blockIdx.x * 256 + threadIdx.x;
    if (e < NE) atomicAdd(&deg[edges[e]], 1);
}

__global__ __launch_bounds__(1024)
void scan_kernel(const int* __restrict__ deg, int* __restrict__ rowptr)
{
    __shared__ int sums[1024];
    const int t = threadIdx.x;
    const int CH = (NN + 1023) / 1024;   // 49
    const int b = t * CH;
    int s = 0;
    for (int i = 0; i < CH; ++i) {
        int idx = b + i;
        if (idx < NN) s += deg[idx];
    }
    sums[t] = s;
    __syncthreads();
    for (int off = 1; off < 1024; off <<= 1) {
        int v = 0;
        if (t >= off) v = sums[t - off];
        __syncthreads();
        if (t >= off) sums[t] += v;
        __syncthreads();
    }
    int run = (t == 0) ? 0 : sums[t - 1];
    for (int i = 0; i < CH; ++i) {
        int idx = b + i;
        if (idx < NN) { rowptr[idx] = run; run += deg[idx]; }
    }
    if (t == 1023) rowptr[NN] = run;
}

__global__ __launch_bounds__(256)
void fill_kernel(const int* __restrict__ edges, const float* __restrict__ ew,
                 const int* __restrict__ rowptr, int* __restrict__ fill,
                 int* __restrict__ colsrc, float* __restrict__ colw)
{
    int e = blockIdx.x * 256 + threadIdx.x;
    if (e >= NE) return;
    int d = edges[e];
    int pos = atomicAdd(&fill[d], 1);
    int idx = rowptr[d] + pos;
    colsrc[idx] = edges[NE + e];
    colw[idx] = ew[e];
}

// ---------------- gather-aggregate: agg[n] = mean_e msg[src_e]*w_e ---------
__global__ __launch_bounds__(256)
void gather_kernel(const int* __restrict__ rowptr, const int* __restrict__ colsrc,
                   const float* __restrict__ colw, const float* __restrict__ msg,
                   float* __restrict__ agg)
{
    int wid = (blockIdx.x * 256 + threadIdx.x) >> 6;   // one wave per node
    int lane = threadIdx.x & 63;
    if (wid >= NN) return;
    int beg = rowptr[wid], end = rowptr[wid + 1];
    float2 acc = make_float2(0.0f, 0.0f);
    for (int j = beg; j < end; ++j) {
        int src = colsrc[j];
        float w = colw[j];
        float2 m = *reinterpret_cast<const float2*>(&msg[(long long)src * HH + lane * 2]);
        acc.x += m.x * w;
        acc.y += m.y * w;
    }
    int degree = end - beg;
    float inv = (degree > 0) ? 1.0f / (float)degree : 0.0f;
    float2 o = make_float2(acc.x * inv, acc.y * inv);
    *reinterpret_cast<float2*>(&agg[(long long)wid * HH + lane * 2]) = o;
}

// ---------------- update FFN over concat(x, agg) ----------------------------
__global__ __launch_bounds__(256)
void upd_kernel(const float* __restrict__ x, const float* __restrict__ agg,
                const float* __restrict__ bn0_g, const float* __restrict__ bn0_b,
                const float* __restrict__ bn0_m, const float* __restrict__ bn0_v,
                const float* __restrict__ W0, const float* __restrict__ b0,
                const float* __restrict__ bn1_g, const float* __restrict__ bn1_b,
                const float* __restrict__ bn1_m, const float* __restrict__ bn1_v,
                const float* __restrict__ W1, const float* __restrict__ b1,
                float* __restrict__ out)
{
    const int K = DD + HH; // 256
    __shared__ float xs[32][256 + 1];
    __shared__ float ys[32][HH + 1];
    const int row0 = blockIdx.x * 32;
    const int tid = threadIdx.x;
    const int tx = tid & 31;
    const int ty = tid >> 5;

    for (int i = tid; i < 32 * 256; i += 256) {
        int r = i >> 8, c = i & 255;
        int row = row0 + r;
        float v = 0.0f;
        if (row < NN) {
            v = (c < DD) ? x[(long long)row * DD + c]
                         : agg[(long long)row * HH + (c - DD)];
        }
        xs[r][c] = (v - bn0_m[c]) * rsqrtf(bn0_v[c] + BN_EPS) * bn0_g[c] + bn0_b[c];
    }
    __syncthreads();

    float acc[4][4];
#pragma unroll
    for (int r = 0; r < 4; ++r)
#pragma unroll
        for (int c = 0; c < 4; ++c) acc[r][c] = 0.0f;

    for (int k = 0; k < K; ++k) {
        float4 w = *reinterpret_cast<const float4*>(&W0[k * HH + tx * 4]);
#pragma unroll
        for (int r = 0; r < 4; ++r) {
            float xv = xs[ty * 4 + r][k];
            acc[r][0] += xv * w.x; acc[r][1] += xv * w.y;
            acc[r][2] += xv * w.z; acc[r][3] += xv * w.w;
        }
    }

#pragma unroll
    for (int c = 0; c < 4; ++c) {
        int col = tx * 4 + c;
        float bias = b0[col];
        float sc = rsqrtf(bn1_v[col] + BN_EPS) * bn1_g[col];
        float mm = bn1_m[col], bb = bn1_b[col];
#pragma unroll
        for (int r = 0; r < 4; ++r) {
            float y = gelu_f(acc[r][c] + bias);
            ys[ty * 4 + r][col] = (y - mm) * sc + bb;
        }
    }
    __syncthreads();

    float acc2[4][4];
#pragma unroll
    for (int r = 0; r < 4; ++r)
#pragma unroll
        for (int c = 0; c < 4; ++c) acc2[r][c] = 0.0f;

    for (int k = 0; k < HH; ++k) {
        float4 w = *reinterpret_cast<const float4*>(&W1[k * HH + tx * 4]);
#pragma unroll
        for (int r = 0; r < 4; ++r) {
            float xv = ys[ty * 4 + r][k];
            acc2[r][0] += xv * w.x; acc2[r][1] += xv * w.y;
            acc2[r][2] += xv * w.z; acc2[r][3] += xv * w.w;
        }
    }

#pragma unroll
    for (int r = 0; r < 4; ++r) {
        int row = row0 + ty * 4 + r;
        if (row < NN) {
            float4 o;
            o.x = gelu_f(acc2[r][0] + b1[tx * 4 + 0]);
            o.y = gelu_f(acc2[r][1] + b1[tx * 4 + 1]);
            o.z = gelu_f(acc2[r][2] + b1[tx * 4 + 2]);
            o.w = gelu_f(acc2[r][3] + b1[tx * 4 + 3]);
            *reinterpret_cast<float4*>(&out[(long long)row * HH + tx * 4]) = o;
        }
    }
}

extern "C" void kernel_launch(void* const* d_in, const int* in_sizes, int n_in,
                              void* d_out, int out_size, void* d_ws, size_t ws_size,
                              hipStream_t stream) {
    const float* node_repr = (const float*)d_in[0];
    const int*   edges     = (const int*)d_in[1];
    const float* ew        = (const float*)d_in[2];

    const float* prep_bn0_g = (const float*)d_in[3];
    const float* prep_bn0_b = (const float*)d_in[4];
    const float* prep_bn0_m = (const float*)d_in[5];
    const float* prep_bn0_v = (const float*)d_in[6];
    const float* prep_W0    = (const float*)d_in[7];
    const float* prep_b0    = (const float*)d_in[8];
    const float* prep_bn1_g = (const float*)d_in[9];
    const float* prep_bn1_b = (const float*)d_in[10];
    const float* prep_bn1_m = (const float*)d_in[11];
    const float* prep_bn1_v = (const float*)d_in[12];
    const float* prep_W1    = (const float*)d_in[13];
    const float* prep_b1    = (const float*)d_in[14];

    const float* upd_bn0_g = (const float*)d_in[15];
    const float* upd_bn0_b = (const float*)d_in[16];
    const float* upd_bn0_m = (const float*)d_in[17];
    const float* upd_bn0_v = (const float*)d_in[18];
    const float* upd_W0    = (const float*)d_in[19];
    const float* upd_b0    = (const float*)d_in[20];
    const float* upd_bn1_g = (const float*)d_in[21];
    const float* upd_bn1_b = (const float*)d_in[22];
    const float* upd_bn1_m = (const float*)d_in[23];
    const float* upd_bn1_v = (const float*)d_in[24];
    const float* upd_W1    = (const float*)d_in[25];
    const float* upd_b1    = (const float*)d_in[26];

    // workspace layout
    float* msg    = (float*)d_ws;                        // NN*HH
    float* agg    = msg + (size_t)NN * HH;               // NN*HH
    int*   deg    = (int*)(agg + (size_t)NN * HH);       // NN
    int*   fill   = deg + NN;                            // NN
    int*   rowptr = fill + NN;                           // NN+1
    int*   colsrc = rowptr + NN + 1;                     // NE
    float* colw   = (float*)(colsrc + NE);               // NE

    hipMemsetAsync(deg, 0, 2 * (size_t)NN * sizeof(int), stream); // deg + fill

    int nblk = (NN + 31) / 32;
    prep_kernel<<<nblk, 256, 0, stream>>>(node_repr,
        prep_bn0_g, prep_bn0_b, prep_bn0_m, prep_bn0_v, prep_W0, prep_b0,
        prep_bn1_g, prep_bn1_b, prep_bn1_m, prep_bn1_v, prep_W1, prep_b1, msg);

    int eblk = (NE + 255) / 256;
    degree_kernel<<<eblk, 256, 0, stream>>>(edges, deg);
    scan_kernel<<<1, 1024, 0, stream>>>(deg, rowptr);
    fill_kernel<<<eblk, 256, 0, stream>>>(edges, ew, rowptr, fill, colsrc, colw);

    int gblk = (NN * 64 + 255) / 256;
    gather_kernel<<<gblk, 256, 0, stream>>>(rowptr, colsrc, colw, msg, agg);

    upd_kernel<<<nblk, 256, 0, stream>>>(node_repr, agg,
        upd_bn0_g, upd_bn0_b, upd_bn0_m, upd_bn0_v, upd_W0, upd_b0,
        upd_bn1_g, upd_bn1_b, upd_bn1_m, upd_bn1_v, upd_W1, upd_b1,
        (float*)d_out);
}

// Round 3
// 404.053 us; speedup vs baseline: 4.0548x; 1.2276x over previous
//
#include <hip/hip_runtime.h>
#include <math.h>

#define NN 50000
#define NE 800000
#define DD 128
#define HH 128
#define BN_EPS 1e-3f

typedef _Float16 f16x8 __attribute__((ext_vector_type(8)));
typedef _Float16 f16x2 __attribute__((ext_vector_type(2)));
typedef float f32x4 __attribute__((ext_vector_type(4)));

__device__ __forceinline__ float gelu_f(float x) {
    return 0.5f * x * (1.0f + erff(x * 0.70710678118654752f));
}

// ---- fold BN into transposed f16 weights + f32 bias ------------------------
// wt[n*K+k] = (f16)(W[k][n] * a_k),  bs[n] = bias[n] + sum_k shift_k * W[k][n]
__global__ __launch_bounds__(256)
void weights_kernel(const float* __restrict__ W, const float* __restrict__ g,
                    const float* __restrict__ bb, const float* __restrict__ m,
                    const float* __restrict__ v, const float* __restrict__ bias,
                    int K, _Float16* __restrict__ wt, float* __restrict__ bs)
{
    __shared__ float red[256];
    const int n = blockIdx.x;       // output column, 0..127
    const int t = threadIdx.x;
    float part = 0.0f;
    for (int k = t; k < K; k += 256) {
        float a = g[k] * rsqrtf(v[k] + BN_EPS);
        float sh = bb[k] - m[k] * a;
        float wv = W[(long long)k * HH + n];
        wt[(long long)n * K + k] = (_Float16)(wv * a);
        part += sh * wv;
    }
    red[t] = part;
    __syncthreads();
    for (int s = 128; s > 0; s >>= 1) {
        if (t < s) red[t] += red[t + s];
        __syncthreads();
    }
    if (t == 0) bs[n] = bias[n] + red[0];
}

// ---- prep FFN (MFMA): msg = gelu(gelu(x@W0'+b0')@W1'+b1')  [f16 out] -------
__global__ __launch_bounds__(256)
void prep_kernel(const float* __restrict__ x,
                 const _Float16* __restrict__ wt0, const float* __restrict__ bs0,
                 const _Float16* __restrict__ wt1, const float* __restrict__ bs1,
                 _Float16* __restrict__ msg)
{
    __shared__ __align__(16) _Float16 xs[64 * DD];
    __shared__ __align__(16) _Float16 ys[64 * HH];
    const int tid = threadIdx.x;
    const int w = tid >> 6, lane = tid & 63;
    const int row0 = blockIdx.x * 64;

    // stage x -> xs (f16, XOR-swizzled 16B slots)
    for (int i = tid; i < 64 * (DD / 8); i += 256) {
        int r = i >> 4;          // DD/8 == 16
        int k8 = i & 15;
        int row = row0 + r;
        f16x8 h;
        if (row < NN) {
            const float4* p = reinterpret_cast<const float4*>(&x[(long long)row * DD + k8 * 8]);
            float4 u0 = p[0], u1 = p[1];
            h[0] = (_Float16)u0.x; h[1] = (_Float16)u0.y; h[2] = (_Float16)u0.z; h[3] = (_Float16)u0.w;
            h[4] = (_Float16)u1.x; h[5] = (_Float16)u1.y; h[6] = (_Float16)u1.z; h[7] = (_Float16)u1.w;
        } else {
            for (int q = 0; q < 8; ++q) h[q] = (_Float16)0.0f;
        }
        int slot = (r * 16 + k8) ^ (r & 7);
        *reinterpret_cast<f16x8*>(&xs[slot * 8]) = h;
    }
    __syncthreads();

    const int cl = lane & 15;
    const int kg = lane >> 4;          // 0..3
    const int rA = w * 16 + cl;        // A row for this lane

    // ---- layer 0 ----
    f32x4 acc[8];
    const f32x4 zero = {0.0f, 0.0f, 0.0f, 0.0f};
#pragma unroll
    for (int ct = 0; ct < 8; ++ct) acc[ct] = zero;

#pragma unroll
    for (int kc = 0; kc < DD / 32; ++kc) {
        int k0 = kc * 32 + kg * 8;
        int slot = (rA * 16 + (k0 >> 3)) ^ (rA & 7);
        f16x8 a = *reinterpret_cast<const f16x8*>(&xs[slot * 8]);
#pragma unroll
        for (int ct = 0; ct < 8; ++ct) {
            int col = ct * 16 + cl;
            f16x8 b = *reinterpret_cast<const f16x8*>(&wt0[(long long)col * DD + k0]);
            acc[ct] = __builtin_amdgcn_mfma_f32_16x16x32_f16(a, b, acc[ct], 0, 0, 0);
        }
    }

    // epilogue 0: bias + gelu -> ys (f16, swizzled)
#pragma unroll
    for (int ct = 0; ct < 8; ++ct) {
        int col = ct * 16 + cl;
        float bias = bs0[col];
#pragma unroll
        for (int rr = 0; rr < 4; ++rr) {
            int r = w * 16 + kg * 4 + rr;   // C/D: row=(lane>>4)*4+reg
            float vv = gelu_f(acc[ct][rr] + bias);
            int slot = (r * 16 + (col >> 3)) ^ (r & 7);
            ys[slot * 8 + (col & 7)] = (_Float16)vv;
        }
    }
    __syncthreads();

    // ---- layer 1 ----
    f32x4 acc2[8];
#pragma unroll
    for (int ct = 0; ct < 8; ++ct) acc2[ct] = zero;

#pragma unroll
    for (int kc = 0; kc < HH / 32; ++kc) {
        int k0 = kc * 32 + kg * 8;
        int slot = (rA * 16 + (k0 >> 3)) ^ (rA & 7);
        f16x8 a = *reinterpret_cast<const f16x8*>(&ys[slot * 8]);
#pragma unroll
        for (int ct = 0; ct < 8; ++ct) {
            int col = ct * 16 + cl;
            f16x8 b = *reinterpret_cast<const f16x8*>(&wt1[(long long)col * HH + k0]);
            acc2[ct] = __builtin_amdgcn_mfma_f32_16x16x32_f16(a, b, acc2[ct], 0, 0, 0);
        }
    }

#pragma unroll
    for (int ct = 0; ct < 8; ++ct) {
        int col = ct * 16 + cl;
        float bias = bs1[col];
#pragma unroll
        for (int rr = 0; rr < 4; ++rr) {
            int row = row0 + w * 16 + kg * 4 + rr;
            if (row < NN)
                msg[(long long)row * HH + col] = (_Float16)gelu_f(acc2[ct][rr] + bias);
        }
    }
}

// ---- CSR build -------------------------------------------------------------
__global__ __launch_bounds__(256)
void degree_kernel(const int* __restrict__ edges, int* __restrict__ deg)
{
    int e = blockIdx.x * 256 + threadIdx.x;
    if (e < NE) atomicAdd(&deg[edges[e]], 1);
}

__global__ __launch_bounds__(1024)
void scan_kernel(const int* __restrict__ deg, int* __restrict__ rowptr)
{
    __shared__ int sums[1024];
    const int t = threadIdx.x;
    const int CH = (NN + 1023) / 1024;
    const int b = t * CH;
    int s = 0;
    for (int i = 0; i < CH; ++i) {
        int idx = b + i;
        if (idx < NN) s += deg[idx];
    }
    sums[t] = s;
    __syncthreads();
    for (int off = 1; off < 1024; off <<= 1) {
        int vv = 0;
        if (t >= off) vv = sums[t - off];
        __syncthreads();
        if (t >= off) sums[t] += vv;
        __syncthreads();
    }
    int run = (t == 0) ? 0 : sums[t - 1];
    for (int i = 0; i < CH; ++i) {
        int idx = b + i;
        if (idx < NN) { rowptr[idx] = run; run += deg[idx]; }
    }
    if (t == 1023) rowptr[NN] = run;
}

__global__ __launch_bounds__(256)
void fill_kernel(const int* __restrict__ edges, const float* __restrict__ ew,
                 const int* __restrict__ rowptr, int* __restrict__ fill,
                 int* __restrict__ colsrc, float* __restrict__ colw)
{
    int e = blockIdx.x * 256 + threadIdx.x;
    if (e >= NE) return;
    int d = edges[e];
    int pos = atomicAdd(&fill[d], 1);
    int idx = rowptr[d] + pos;
    colsrc[idx] = edges[NE + e];
    colw[idx] = ew[e];
}

// ---- gather-aggregate (f16 msg -> f16 agg) ---------------------------------
__global__ __launch_bounds__(256)
void gather_kernel(const int* __restrict__ rowptr, const int* __restrict__ colsrc,
                   const float* __restrict__ colw, const _Float16* __restrict__ msg,
                   _Float16* __restrict__ aggh)
{
    int wid = (blockIdx.x * 256 + threadIdx.x) >> 6;
    int lane = threadIdx.x & 63;
    if (wid >= NN) return;
    int beg = rowptr[wid], end = rowptr[wid + 1];
    float ax = 0.0f, ay = 0.0f;
    for (int j = beg; j < end; ++j) {
        int src = colsrc[j];
        float w = colw[j];
        f16x2 mm = *reinterpret_cast<const f16x2*>(&msg[(long long)src * HH + lane * 2]);
        ax += (float)mm[0] * w;
        ay += (float)mm[1] * w;
    }
    int degree = end - beg;
    float inv = (degree > 0) ? 1.0f / (float)degree : 0.0f;
    f16x2 o;
    o[0] = (_Float16)(ax * inv);
    o[1] = (_Float16)(ay * inv);
    *reinterpret_cast<f16x2*>(&aggh[(long long)wid * HH + lane * 2]) = o;
}

// ---- update FFN (MFMA) over concat(x, agg), K=256 --------------------------
__global__ __launch_bounds__(256)
void upd_kernel(const float* __restrict__ x, const _Float16* __restrict__ aggh,
                const _Float16* __restrict__ wt2, const float* __restrict__ bs2,
                const _Float16* __restrict__ wt3, const float* __restrict__ bs3,
                float* __restrict__ out)
{
    const int KK = DD + HH;  // 256
    __shared__ __align__(16) _Float16 xs[64 * 256];
    __shared__ __align__(16) _Float16 ys[64 * HH];
    const int tid = threadIdx.x;
    const int w = tid >> 6, lane = tid & 63;
    const int row0 = blockIdx.x * 64;

    // stage concat(x f32, aggh f16) -> xs (f16, swizzled)
    for (int i = tid; i < 64 * (KK / 8); i += 256) {
        int r = i >> 5;          // KK/8 == 32
        int k8 = i & 31;
        int row = row0 + r;
        f16x8 h;
        if (row < NN) {
            if (k8 < 16) {
                const float4* p = reinterpret_cast<const float4*>(&x[(long long)row * DD + k8 * 8]);
                float4 u0 = p[0], u1 = p[1];
                h[0] = (_Float16)u0.x; h[1] = (_Float16)u0.y; h[2] = (_Float16)u0.z; h[3] = (_Float16)u0.w;
                h[4] = (_Float16)u1.x; h[5] = (_Float16)u1.y; h[6] = (_Float16)u1.z; h[7] = (_Float16)u1.w;
            } else {
                h = *reinterpret_cast<const f16x8*>(&aggh[(long long)row * HH + (k8 - 16) * 8]);
            }
        } else {
            for (int q = 0; q < 8; ++q) h[q] = (_Float16)0.0f;
        }
        int slot = (r * 32 + k8) ^ (r & 7);
        *reinterpret_cast<f16x8*>(&xs[slot * 8]) = h;
    }
    __syncthreads();

    const int cl = lane & 15;
    const int kg = lane >> 4;
    const int rA = w * 16 + cl;

    f32x4 acc[8];
    const f32x4 zero = {0.0f, 0.0f, 0.0f, 0.0f};
#pragma unroll
    for (int ct = 0; ct < 8; ++ct) acc[ct] = zero;

#pragma unroll
    for (int kc = 0; kc < 256 / 32; ++kc) {
        int k0 = kc * 32 + kg * 8;
        int slot = (rA * 32 + (k0 >> 3)) ^ (rA & 7);
        f16x8 a = *reinterpret_cast<const f16x8*>(&xs[slot * 8]);
#pragma unroll
        for (int ct = 0; ct < 8; ++ct) {
            int col = ct * 16 + cl;
            f16x8 b = *reinterpret_cast<const f16x8*>(&wt2[(long long)col * 256 + k0]);
            acc[ct] = __builtin_amdgcn_mfma_f32_16x16x32_f16(a, b, acc[ct], 0, 0, 0);
        }
    }

#pragma unroll
    for (int ct = 0; ct < 8; ++ct) {
        int col = ct * 16 + cl;
        float bias = bs2[col];
#pragma unroll
        for (int rr = 0; rr < 4; ++rr) {
            int r = w * 16 + kg * 4 + rr;
            float vv = gelu_f(acc[ct][rr] + bias);
            int slot = (r * 16 + (col >> 3)) ^ (r & 7);
            ys[slot * 8 + (col & 7)] = (_Float16)vv;
        }
    }
    __syncthreads();

    f32x4 acc2[8];
#pragma unroll
    for (int ct = 0; ct < 8; ++ct) acc2[ct] = zero;

#pragma unroll
    for (int kc = 0; kc < HH / 32; ++kc) {
        int k0 = kc * 32 + kg * 8;
        int slot = (rA * 16 + (k0 >> 3)) ^ (rA & 7);
        f16x8 a = *reinterpret_cast<const f16x8*>(&ys[slot * 8]);
#pragma unroll
        for (int ct = 0; ct < 8; ++ct) {
            int col = ct * 16 + cl;
            f16x8 b = *reinterpret_cast<const f16x8*>(&wt3[(long long)col * HH + k0]);
            acc2[ct] = __builtin_amdgcn_mfma_f32_16x16x32_f16(a, b, acc2[ct], 0, 0, 0);
        }
    }

#pragma unroll
    for (int ct = 0; ct < 8; ++ct) {
        int col = ct * 16 + cl;
        float bias = bs3[col];
#pragma unroll
        for (int rr = 0; rr < 4; ++rr) {
            int row = row0 + w * 16 + kg * 4 + rr;
            if (row < NN)
                out[(long long)row * HH + col] = gelu_f(acc2[ct][rr] + bias);
        }
    }
}

extern "C" void kernel_launch(void* const* d_in, const int* in_sizes, int n_in,
                              void* d_out, int out_size, void* d_ws, size_t ws_size,
                              hipStream_t stream) {
    const float* node_repr = (const float*)d_in[0];
    const int*   edges     = (const int*)d_in[1];
    const float* ew        = (const float*)d_in[2];

    const float* prep_bn0_g = (const float*)d_in[3];
    const float* prep_bn0_b = (const float*)d_in[4];
    const float* prep_bn0_m = (const float*)d_in[5];
    const float* prep_bn0_v = (const float*)d_in[6];
    const float* prep_W0    = (const float*)d_in[7];
    const float* prep_b0    = (const float*)d_in[8];
    const float* prep_bn1_g = (const float*)d_in[9];
    const float* prep_bn1_b = (const float*)d_in[10];
    const float* prep_bn1_m = (const float*)d_in[11];
    const float* prep_bn1_v = (const float*)d_in[12];
    const float* prep_W1    = (const float*)d_in[13];
    const float* prep_b1    = (const float*)d_in[14];

    const float* upd_bn0_g = (const float*)d_in[15];
    const float* upd_bn0_b = (const float*)d_in[16];
    const float* upd_bn0_m = (const float*)d_in[17];
    const float* upd_bn0_v = (const float*)d_in[18];
    const float* upd_W0    = (const float*)d_in[19];
    const float* upd_b0    = (const float*)d_in[20];
    const float* upd_bn1_g = (const float*)d_in[21];
    const float* upd_bn1_b = (const float*)d_in[22];
    const float* upd_bn1_m = (const float*)d_in[23];
    const float* upd_bn1_v = (const float*)d_in[24];
    const float* upd_W1    = (const float*)d_in[25];
    const float* upd_b1    = (const float*)d_in[26];

    // workspace layout
    _Float16* msg  = (_Float16*)d_ws;                 // NN*HH
    _Float16* aggh = msg + (size_t)NN * HH;           // NN*HH
    _Float16* wt0  = aggh + (size_t)NN * HH;          // 128*128
    _Float16* wt1  = wt0 + 128 * 128;                 // 128*128
    _Float16* wt2  = wt1 + 128 * 128;                 // 128*256
    _Float16* wt3  = wt2 + 128 * 256;                 // 128*128
    float* bs0 = (float*)(wt3 + 128 * 128);           // 128 each
    float* bs1 = bs0 + 128;
    float* bs2 = bs1 + 128;
    float* bs3 = bs2 + 128;
    int* deg    = (int*)(bs3 + 128);                  // NN
    int* fill   = deg + NN;                           // NN
    int* rowptr = fill + NN;                          // NN+1
    int* colsrc = rowptr + NN + 1;                    // NE
    float* colw = (float*)(colsrc + NE);              // NE

    hipMemsetAsync(deg, 0, 2 * (size_t)NN * sizeof(int), stream);

    weights_kernel<<<128, 256, 0, stream>>>(prep_W0, prep_bn0_g, prep_bn0_b, prep_bn0_m,
                                            prep_bn0_v, prep_b0, DD, wt0, bs0);
    weights_kernel<<<128, 256, 0, stream>>>(prep_W1, prep_bn1_g, prep_bn1_b, prep_bn1_m,
                                            prep_bn1_v, prep_b1, HH, wt1, bs1);
    weights_kernel<<<128, 256, 0, stream>>>(upd_W0, upd_bn0_g, upd_bn0_b, upd_bn0_m,
                                            upd_bn0_v, upd_b0, DD + HH, wt2, bs2);
    weights_kernel<<<128, 256, 0, stream>>>(upd_W1, upd_bn1_g, upd_bn1_b, upd_bn1_m,
                                            upd_bn1_v, upd_b1, HH, wt3, bs3);

    int nblk = (NN + 63) / 64;
    prep_kernel<<<nblk, 256, 0, stream>>>(node_repr, wt0, bs0, wt1, bs1, msg);

    int eblk = (NE + 255) / 256;
    degree_kernel<<<eblk, 256, 0, stream>>>(edges, deg);
    scan_kernel<<<1, 1024, 0, stream>>>(deg, rowptr);
    fill_kernel<<<eblk, 256, 0, stream>>>(edges, ew, rowptr, fill, colsrc, colw);

    int gblk = ((size_t)NN * 64 + 255) / 256;
    gather_kernel<<<gblk, 256, 0, stream>>>(rowptr, colsrc, colw, msg, aggh);

    upd_kernel<<<nblk, 256, 0, stream>>>(node_repr, aggh, wt2, bs2, wt3, bs3,
                                         (float*)d_out);
}

// Round 4
// 273.511 us; speedup vs baseline: 5.9901x; 1.4773x over previous
//
#include <hip/hip_runtime.h>
#include <math.h>

#define NN 50000
#define NE 800000
#define DD 128
#define HH 128
#define BN_EPS 1e-3f
#define SCB 196   // ceil(NN/256)

typedef _Float16 f16x8 __attribute__((ext_vector_type(8)));
typedef float f32x4 __attribute__((ext_vector_type(4)));

__device__ __forceinline__ float gelu_f(float x) {
    return 0.5f * x * (1.0f + erff(x * 0.70710678118654752f));
}

// ---- fold BN into transposed f16 weights + f32 bias ------------------------
__global__ __launch_bounds__(256)
void weights_kernel(const float* __restrict__ W, const float* __restrict__ g,
                    const float* __restrict__ bb, const float* __restrict__ m,
                    const float* __restrict__ v, const float* __restrict__ bias,
                    int K, _Float16* __restrict__ wt, float* __restrict__ bs)
{
    __shared__ float red[256];
    const int n = blockIdx.x;
    const int t = threadIdx.x;
    float part = 0.0f;
    for (int k = t; k < K; k += 256) {
        float a = g[k] * rsqrtf(v[k] + BN_EPS);
        float sh = bb[k] - m[k] * a;
        float wv = W[(long long)k * HH + n];
        wt[(long long)n * K + k] = (_Float16)(wv * a);
        part += sh * wv;
    }
    red[t] = part;
    __syncthreads();
    for (int s = 128; s > 0; s >>= 1) {
        if (t < s) red[t] += red[t + s];
        __syncthreads();
    }
    if (t == 0) bs[n] = bias[n] + red[0];
}

// ---- prep FFN (MFMA), ys aliases xs ---------------------------------------
__global__ __launch_bounds__(256)
void prep_kernel(const float* __restrict__ x,
                 const _Float16* __restrict__ wt0, const float* __restrict__ bs0,
                 const _Float16* __restrict__ wt1, const float* __restrict__ bs1,
                 _Float16* __restrict__ msg)
{
    __shared__ __align__(16) _Float16 smem[64 * DD];   // 16 KB, xs then ys
    const int tid = threadIdx.x;
    const int w = tid >> 6, lane = tid & 63;
    const int row0 = blockIdx.x * 64;

    for (int i = tid; i < 64 * (DD / 8); i += 256) {
        int r = i >> 4;
        int k8 = i & 15;
        int row = row0 + r;
        f16x8 h;
        if (row < NN) {
            const float4* p = reinterpret_cast<const float4*>(&x[(long long)row * DD + k8 * 8]);
            float4 u0 = p[0], u1 = p[1];
            h[0] = (_Float16)u0.x; h[1] = (_Float16)u0.y; h[2] = (_Float16)u0.z; h[3] = (_Float16)u0.w;
            h[4] = (_Float16)u1.x; h[5] = (_Float16)u1.y; h[6] = (_Float16)u1.z; h[7] = (_Float16)u1.w;
        } else {
#pragma unroll
            for (int q = 0; q < 8; ++q) h[q] = (_Float16)0.0f;
        }
        int slot = (r * 16 + k8) ^ (r & 7);
        *reinterpret_cast<f16x8*>(&smem[slot * 8]) = h;
    }
    __syncthreads();

    const int cl = lane & 15;
    const int kg = lane >> 4;
    const int rA = w * 16 + cl;

    f32x4 acc[8];
    const f32x4 zero = {0.0f, 0.0f, 0.0f, 0.0f};
#pragma unroll
    for (int ct = 0; ct < 8; ++ct) acc[ct] = zero;

#pragma unroll
    for (int kc = 0; kc < DD / 32; ++kc) {
        int k0 = kc * 32 + kg * 8;
        int slot = (rA * 16 + (k0 >> 3)) ^ (rA & 7);
        f16x8 a = *reinterpret_cast<const f16x8*>(&smem[slot * 8]);
#pragma unroll
        for (int ct = 0; ct < 8; ++ct) {
            int col = ct * 16 + cl;
            f16x8 b = *reinterpret_cast<const f16x8*>(&wt0[(long long)col * DD + k0]);
            acc[ct] = __builtin_amdgcn_mfma_f32_16x16x32_f16(a, b, acc[ct], 0, 0, 0);
        }
    }
    __syncthreads();   // all xs reads done; smem now becomes ys

#pragma unroll
    for (int ct = 0; ct < 8; ++ct) {
        int col = ct * 16 + cl;
        float bias = bs0[col];
#pragma unroll
        for (int rr = 0; rr < 4; ++rr) {
            int r = w * 16 + kg * 4 + rr;
            float vv = gelu_f(acc[ct][rr] + bias);
            int slot = (r * 16 + (col >> 3)) ^ (r & 7);
            smem[slot * 8 + (col & 7)] = (_Float16)vv;
        }
    }
    __syncthreads();

    f32x4 acc2[8];
#pragma unroll
    for (int ct = 0; ct < 8; ++ct) acc2[ct] = zero;

#pragma unroll
    for (int kc = 0; kc < HH / 32; ++kc) {
        int k0 = kc * 32 + kg * 8;
        int slot = (rA * 16 + (k0 >> 3)) ^ (rA & 7);
        f16x8 a = *reinterpret_cast<const f16x8*>(&smem[slot * 8]);
#pragma unroll
        for (int ct = 0; ct < 8; ++ct) {
            int col = ct * 16 + cl;
            f16x8 b = *reinterpret_cast<const f16x8*>(&wt1[(long long)col * HH + k0]);
            acc2[ct] = __builtin_amdgcn_mfma_f32_16x16x32_f16(a, b, acc2[ct], 0, 0, 0);
        }
    }

#pragma unroll
    for (int ct = 0; ct < 8; ++ct) {
        int col = ct * 16 + cl;
        float bias = bs1[col];
#pragma unroll
        for (int rr = 0; rr < 4; ++rr) {
            int row = row0 + w * 16 + kg * 4 + rr;
            if (row < NN)
                msg[(long long)row * HH + col] = (_Float16)gelu_f(acc2[ct][rr] + bias);
        }
    }
}

// ---- CSR build -------------------------------------------------------------
__global__ __launch_bounds__(256)
void degree_kernel(const int* __restrict__ edges, int* __restrict__ deg)
{
    int e = blockIdx.x * 256 + threadIdx.x;
    if (e < NE) atomicAdd(&deg[edges[e]], 1);
}

__global__ __launch_bounds__(256)
void scan_partial_kernel(const int* __restrict__ deg, int* __restrict__ part)
{
    __shared__ int red[256];
    int t = threadIdx.x;
    int i = blockIdx.x * 256 + t;
    red[t] = (i < NN) ? deg[i] : 0;
    __syncthreads();
    for (int s = 128; s > 0; s >>= 1) {
        if (t < s) red[t] += red[t + s];
        __syncthreads();
    }
    if (t == 0) part[blockIdx.x] = red[0];
}

__global__ __launch_bounds__(256)
void scan_offsets_kernel(const int* __restrict__ part, int* __restrict__ boff)
{
    __shared__ int s[256];
    int t = threadIdx.x;
    s[t] = (t < SCB) ? part[t] : 0;
    __syncthreads();
    for (int off = 1; off < 256; off <<= 1) {
        int v = (t >= off) ? s[t - off] : 0;
        __syncthreads();
        s[t] += v;
        __syncthreads();
    }
    boff[t] = (t == 0) ? 0 : s[t - 1];
}

__global__ __launch_bounds__(256)
void scan_write_kernel(const int* __restrict__ deg, const int* __restrict__ boff,
                       int* __restrict__ rowptr)
{
    __shared__ int s[256];
    int t = threadIdx.x, b = blockIdx.x;
    int i = b * 256 + t;
    int v = (i < NN) ? deg[i] : 0;
    s[t] = v;
    __syncthreads();
    for (int off = 1; off < 256; off <<= 1) {
        int u = (t >= off) ? s[t - off] : 0;
        __syncthreads();
        s[t] += u;
        __syncthreads();
    }
    if (i < NN) rowptr[i] = boff[b] + (s[t] - v);
    if (b == SCB - 1 && t == 255) rowptr[NN] = boff[b] + s[255];
}

__global__ __launch_bounds__(256)
void fill_kernel(const int* __restrict__ edges, const float* __restrict__ ew,
                 const int* __restrict__ rowptr, int* __restrict__ fill,
                 int* __restrict__ colsrc, float* __restrict__ colw)
{
    int e = blockIdx.x * 256 + threadIdx.x;
    if (e >= NE) return;
    int d = edges[e];
    int pos = atomicAdd(&fill[d], 1);
    int idx = rowptr[d] + pos;
    colsrc[idx] = edges[NE + e];
    colw[idx] = ew[e];
}

// ---- gather-aggregate: 4 nodes per wave, f16x8 per lane --------------------
__global__ __launch_bounds__(256)
void gather_kernel(const int* __restrict__ rowptr, const int* __restrict__ colsrc,
                   const float* __restrict__ colw, const _Float16* __restrict__ msg,
                   _Float16* __restrict__ aggh)
{
    int gwave = (blockIdx.x * 256 + threadIdx.x) >> 6;
    int lane = threadIdx.x & 63;
    int sub = lane >> 4, l16 = lane & 15;
    int node = gwave * 4 + sub;
    if (node >= NN) return;
    int beg = rowptr[node], end = rowptr[node + 1];
    float acc[8];
#pragma unroll
    for (int q = 0; q < 8; ++q) acc[q] = 0.0f;
    for (int j = beg; j < end; ++j) {
        int src = colsrc[j];
        float w = colw[j];
        f16x8 m = *reinterpret_cast<const f16x8*>(&msg[(long long)src * HH + l16 * 8]);
#pragma unroll
        for (int q = 0; q < 8; ++q) acc[q] += (float)m[q] * w;
    }
    float inv = (end > beg) ? 1.0f / (float)(end - beg) : 0.0f;
    f16x8 o;
#pragma unroll
    for (int q = 0; q < 8; ++q) o[q] = (_Float16)(acc[q] * inv);
    *reinterpret_cast<f16x8*>(&aggh[(long long)node * HH + l16 * 8]) = o;
}

// ---- update FFN (MFMA) over concat(x, agg), ys aliases xs ------------------
__global__ __launch_bounds__(256)
void upd_kernel(const float* __restrict__ x, const _Float16* __restrict__ aggh,
                const _Float16* __restrict__ wt2, const float* __restrict__ bs2,
                const _Float16* __restrict__ wt3, const float* __restrict__ bs3,
                float* __restrict__ out)
{
    const int KK = DD + HH;  // 256
    __shared__ __align__(16) _Float16 smem[64 * 256];   // 32 KB, xs then ys
    const int tid = threadIdx.x;
    const int w = tid >> 6, lane = tid & 63;
    const int row0 = blockIdx.x * 64;

    for (int i = tid; i < 64 * (KK / 8); i += 256) {
        int r = i >> 5;
        int k8 = i & 31;
        int row = row0 + r;
        f16x8 h;
        if (row < NN) {
            if (k8 < 16) {
                const float4* p = reinterpret_cast<const float4*>(&x[(long long)row * DD + k8 * 8]);
                float4 u0 = p[0], u1 = p[1];
                h[0] = (_Float16)u0.x; h[1] = (_Float16)u0.y; h[2] = (_Float16)u0.z; h[3] = (_Float16)u0.w;
                h[4] = (_Float16)u1.x; h[5] = (_Float16)u1.y; h[6] = (_Float16)u1.z; h[7] = (_Float16)u1.w;
            } else {
                h = *reinterpret_cast<const f16x8*>(&aggh[(long long)row * HH + (k8 - 16) * 8]);
            }
        } else {
#pragma unroll
            for (int q = 0; q < 8; ++q) h[q] = (_Float16)0.0f;
        }
        int slot = (r * 32 + k8) ^ (r & 7);
        *reinterpret_cast<f16x8*>(&smem[slot * 8]) = h;
    }
    __syncthreads();

    const int cl = lane & 15;
    const int kg = lane >> 4;
    const int rA = w * 16 + cl;

    f32x4 acc[8];
    const f32x4 zero = {0.0f, 0.0f, 0.0f, 0.0f};
#pragma unroll
    for (int ct = 0; ct < 8; ++ct) acc[ct] = zero;

#pragma unroll
    for (int kc = 0; kc < 256 / 32; ++kc) {
        int k0 = kc * 32 + kg * 8;
        int slot = (rA * 32 + (k0 >> 3)) ^ (rA & 7);
        f16x8 a = *reinterpret_cast<const f16x8*>(&smem[slot * 8]);
#pragma unroll
        for (int ct = 0; ct < 8; ++ct) {
            int col = ct * 16 + cl;
            f16x8 b = *reinterpret_cast<const f16x8*>(&wt2[(long long)col * 256 + k0]);
            acc[ct] = __builtin_amdgcn_mfma_f32_16x16x32_f16(a, b, acc[ct], 0, 0, 0);
        }
    }
    __syncthreads();   // xs reads done; smem becomes ys

#pragma unroll
    for (int ct = 0; ct < 8; ++ct) {
        int col = ct * 16 + cl;
        float bias = bs2[col];
#pragma unroll
        for (int rr = 0; rr < 4; ++rr) {
            int r = w * 16 + kg * 4 + rr;
            float vv = gelu_f(acc[ct][rr] + bias);
            int slot = (r * 16 + (col >> 3)) ^ (r & 7);
            smem[slot * 8 + (col & 7)] = (_Float16)vv;
        }
    }
    __syncthreads();

    f32x4 acc2[8];
#pragma unroll
    for (int ct = 0; ct < 8; ++ct) acc2[ct] = zero;

#pragma unroll
    for (int kc = 0; kc < HH / 32; ++kc) {
        int k0 = kc * 32 + kg * 8;
        int slot = (rA * 16 + (k0 >> 3)) ^ (rA & 7);
        f16x8 a = *reinterpret_cast<const f16x8*>(&smem[slot * 8]);
#pragma unroll
        for (int ct = 0; ct < 8; ++ct) {
            int col = ct * 16 + cl;
            f16x8 b = *reinterpret_cast<const f16x8*>(&wt3[(long long)col * HH + k0]);
            acc2[ct] = __builtin_amdgcn_mfma_f32_16x16x32_f16(a, b, acc2[ct], 0, 0, 0);
        }
    }

#pragma unroll
    for (int ct = 0; ct < 8; ++ct) {
        int col = ct * 16 + cl;
        float bias = bs3[col];
#pragma unroll
        for (int rr = 0; rr < 4; ++rr) {
            int row = row0 + w * 16 + kg * 4 + rr;
            if (row < NN)
                out[(long long)row * HH + col] = gelu_f(acc2[ct][rr] + bias);
        }
    }
}

extern "C" void kernel_launch(void* const* d_in, const int* in_sizes, int n_in,
                              void* d_out, int out_size, void* d_ws, size_t ws_size,
                              hipStream_t stream) {
    const float* node_repr = (const float*)d_in[0];
    const int*   edges     = (const int*)d_in[1];
    const float* ew        = (const float*)d_in[2];

    const float* prep_bn0_g = (const float*)d_in[3];
    const float* prep_bn0_b = (const float*)d_in[4];
    const float* prep_bn0_m = (const float*)d_in[5];
    const float* prep_bn0_v = (const float*)d_in[6];
    const float* prep_W0    = (const float*)d_in[7];
    const float* prep_b0    = (const float*)d_in[8];
    const float* prep_bn1_g = (const float*)d_in[9];
    const float* prep_bn1_b = (const float*)d_in[10];
    const float* prep_bn1_m = (const float*)d_in[11];
    const float* prep_bn1_v = (const float*)d_in[12];
    const float* prep_W1    = (const float*)d_in[13];
    const float* prep_b1    = (const float*)d_in[14];

    const float* upd_bn0_g = (const float*)d_in[15];
    const float* upd_bn0_b = (const float*)d_in[16];
    const float* upd_bn0_m = (const float*)d_in[17];
    const float* upd_bn0_v = (const float*)d_in[18];
    const float* upd_W0    = (const float*)d_in[19];
    const float* upd_b0    = (const float*)d_in[20];
    const float* upd_bn1_g = (const float*)d_in[21];
    const float* upd_bn1_b = (const float*)d_in[22];
    const float* upd_bn1_m = (const float*)d_in[23];
    const float* upd_bn1_v = (const float*)d_in[24];
    const float* upd_W1    = (const float*)d_in[25];
    const float* upd_b1    = (const float*)d_in[26];

    // workspace layout
    _Float16* msg  = (_Float16*)d_ws;                 // NN*HH
    _Float16* aggh = msg + (size_t)NN * HH;           // NN*HH
    _Float16* wt0  = aggh + (size_t)NN * HH;          // 128*128
    _Float16* wt1  = wt0 + 128 * 128;                 // 128*128
    _Float16* wt2  = wt1 + 128 * 128;                 // 128*256
    _Float16* wt3  = wt2 + 128 * 256;                 // 128*128
    float* bs0 = (float*)(wt3 + 128 * 128);
    float* bs1 = bs0 + 128;
    float* bs2 = bs1 + 128;
    float* bs3 = bs2 + 128;
    int* deg    = (int*)(bs3 + 128);                  // NN
    int* fill   = deg + NN;                           // NN
    int* rowptr = fill + NN;                          // NN+1
    int* part   = rowptr + NN + 1;                    // 256
    int* boff   = part + 256;                         // 256
    int* colsrc = boff + 256;                         // NE
    float* colw = (float*)(colsrc + NE);              // NE

    hipMemsetAsync(deg, 0, 2 * (size_t)NN * sizeof(int), stream);

    weights_kernel<<<128, 256, 0, stream>>>(prep_W0, prep_bn0_g, prep_bn0_b, prep_bn0_m,
                                            prep_bn0_v, prep_b0, DD, wt0, bs0);
    weights_kernel<<<128, 256, 0, stream>>>(prep_W1, prep_bn1_g, prep_bn1_b, prep_bn1_m,
                                            prep_bn1_v, prep_b1, HH, wt1, bs1);
    weights_kernel<<<128, 256, 0, stream>>>(upd_W0, upd_bn0_g, upd_bn0_b, upd_bn0_m,
                                            upd_bn0_v, upd_b0, DD + HH, wt2, bs2);
    weights_kernel<<<128, 256, 0, stream>>>(upd_W1, upd_bn1_g, upd_bn1_b, upd_bn1_m,
                                            upd_bn1_v, upd_b1, HH, wt3, bs3);

    int nblk = (NN + 63) / 64;
    prep_kernel<<<nblk, 256, 0, stream>>>(node_repr, wt0, bs0, wt1, bs1, msg);

    int eblk = (NE + 255) / 256;
    degree_kernel<<<eblk, 256, 0, stream>>>(edges, deg);
    scan_partial_kernel<<<SCB, 256, 0, stream>>>(deg, part);
    scan_offsets_kernel<<<1, 256, 0, stream>>>(part, boff);
    scan_write_kernel<<<SCB, 256, 0, stream>>>(deg, boff, rowptr);
    fill_kernel<<<eblk, 256, 0, stream>>>(edges, ew, rowptr, fill, colsrc, colw);

    int gblk = (NN + 15) / 16;   // 16 nodes per block (4 waves x 4 nodes)
    gather_kernel<<<gblk, 256, 0, stream>>>(rowptr, colsrc, colw, msg, aggh);

    upd_kernel<<<nblk, 256, 0, stream>>>(node_repr, aggh, wt2, bs2, wt3, bs3,
                                         (float*)d_out);
}

// Round 6
// 228.736 us; speedup vs baseline: 7.1627x; 1.1957x over previous
//
#include <hip/hip_runtime.h>
#include <math.h>

#define NN 50000
#define NE 800000
#define DD 128
#define HH 128
#define BN_EPS 1e-3f
#define SCB 196   // ceil(NN/256)

typedef _Float16 f16x8 __attribute__((ext_vector_type(8)));
typedef float f32x4 __attribute__((ext_vector_type(4)));

__device__ __forceinline__ float gelu_f(float x) {
    return 0.5f * x * (1.0f + erff(x * 0.70710678118654752f));
}

// ---- fold BN into transposed f16 weights + f32 bias ------------------------
__global__ __launch_bounds__(256)
void weights_kernel(const float* __restrict__ W, const float* __restrict__ g,
                    const float* __restrict__ bb, const float* __restrict__ m,
                    const float* __restrict__ v, const float* __restrict__ bias,
                    int K, _Float16* __restrict__ wt, float* __restrict__ bs)
{
    __shared__ float red[256];
    const int n = blockIdx.x;
    const int t = threadIdx.x;
    float part = 0.0f;
    for (int k = t; k < K; k += 256) {
        float a = g[k] * rsqrtf(v[k] + BN_EPS);
        float sh = bb[k] - m[k] * a;
        float wv = W[(long long)k * HH + n];
        wt[(long long)n * K + k] = (_Float16)(wv * a);
        part += sh * wv;
    }
    red[t] = part;
    __syncthreads();
    for (int s = 128; s > 0; s >>= 1) {
        if (t < s) red[t] += red[t + s];
        __syncthreads();
    }
    if (t == 0) bs[n] = bias[n] + red[0];
}

// ---- prep FFN (MFMA, reg-resident B): 32 rows/block ------------------------
__global__ __launch_bounds__(256, 4)
void prep_kernel(const float* __restrict__ x,
                 const _Float16* __restrict__ wt0, const float* __restrict__ bs0,
                 const _Float16* __restrict__ wt1, const float* __restrict__ bs1,
                 _Float16* __restrict__ msg)
{
    __shared__ __align__(16) _Float16 smem[32 * DD];   // 8 KB, xs then ys
    const int tid = threadIdx.x;
    const int w = tid >> 6, lane = tid & 63;
    const int row0 = blockIdx.x * 32;
    const int cl = lane & 15;
    const int kg = lane >> 4;

    // layer-0 B fragments: this wave's 32 cols, all K
    f16x8 b0[4][2];
#pragma unroll
    for (int kc = 0; kc < 4; ++kc)
#pragma unroll
        for (int ct = 0; ct < 2; ++ct) {
            int col = w * 32 + ct * 16 + cl;
            b0[kc][ct] = *reinterpret_cast<const f16x8*>(&wt0[(long long)col * DD + kc * 32 + kg * 8]);
        }

    // stage x -> smem (f16, swizzled)
    for (int i = tid; i < 32 * (DD / 8); i += 256) {
        int r = i >> 4, k8 = i & 15;
        int row = row0 + r;
        f16x8 h;
        if (row < NN) {
            const float4* p = reinterpret_cast<const float4*>(&x[(long long)row * DD + k8 * 8]);
            float4 u0 = p[0], u1 = p[1];
            h[0] = (_Float16)u0.x; h[1] = (_Float16)u0.y; h[2] = (_Float16)u0.z; h[3] = (_Float16)u0.w;
            h[4] = (_Float16)u1.x; h[5] = (_Float16)u1.y; h[6] = (_Float16)u1.z; h[7] = (_Float16)u1.w;
        } else {
#pragma unroll
            for (int q = 0; q < 8; ++q) h[q] = (_Float16)0.0f;
        }
        int slot = (r * 16 + k8) ^ (r & 7);
        *reinterpret_cast<f16x8*>(&smem[slot * 8]) = h;
    }
    __syncthreads();

    const f32x4 zero = {0.0f, 0.0f, 0.0f, 0.0f};
    f32x4 acc[2][2];
#pragma unroll
    for (int rt = 0; rt < 2; ++rt)
#pragma unroll
        for (int ct = 0; ct < 2; ++ct) acc[rt][ct] = zero;

#pragma unroll
    for (int kc = 0; kc < 4; ++kc) {
        int k8 = kc * 4 + kg;
#pragma unroll
        for (int rt = 0; rt < 2; ++rt) {
            int rA = rt * 16 + cl;
            int slot = (rA * 16 + k8) ^ (rA & 7);
            f16x8 a = *reinterpret_cast<const f16x8*>(&smem[slot * 8]);
#pragma unroll
            for (int ct = 0; ct < 2; ++ct)
                acc[rt][ct] = __builtin_amdgcn_mfma_f32_16x16x32_f16(a, b0[kc][ct], acc[rt][ct], 0, 0, 0);
        }
    }

    // layer-1 B fragments (b0 now dead; latency overlaps epilogue)
    f16x8 b1[4][2];
#pragma unroll
    for (int kc = 0; kc < 4; ++kc)
#pragma unroll
        for (int ct = 0; ct < 2; ++ct) {
            int col = w * 32 + ct * 16 + cl;
            b1[kc][ct] = *reinterpret_cast<const f16x8*>(&wt1[(long long)col * HH + kc * 32 + kg * 8]);
        }

    __syncthreads();   // all xs reads done; smem becomes ys

#pragma unroll
    for (int ct = 0; ct < 2; ++ct) {
        int col = w * 32 + ct * 16 + cl;
        float bias = bs0[col];
#pragma unroll
        for (int rt = 0; rt < 2; ++rt)
#pragma unroll
            for (int rr = 0; rr < 4; ++rr) {
                int r = rt * 16 + kg * 4 + rr;
                float vv = gelu_f(acc[rt][ct][rr] + bias);
                int slot = (r * 16 + (col >> 3)) ^ (r & 7);
                smem[slot * 8 + (col & 7)] = (_Float16)vv;
            }
    }
    __syncthreads();

    f32x4 acc2[2][2];
#pragma unroll
    for (int rt = 0; rt < 2; ++rt)
#pragma unroll
        for (int ct = 0; ct < 2; ++ct) acc2[rt][ct] = zero;

#pragma unroll
    for (int kc = 0; kc < 4; ++kc) {
        int k8 = kc * 4 + kg;
#pragma unroll
        for (int rt = 0; rt < 2; ++rt) {
            int rA = rt * 16 + cl;
            int slot = (rA * 16 + k8) ^ (rA & 7);
            f16x8 a = *reinterpret_cast<const f16x8*>(&smem[slot * 8]);
#pragma unroll
            for (int ct = 0; ct < 2; ++ct)
                acc2[rt][ct] = __builtin_amdgcn_mfma_f32_16x16x32_f16(a, b1[kc][ct], acc2[rt][ct], 0, 0, 0);
        }
    }

#pragma unroll
    for (int ct = 0; ct < 2; ++ct) {
        int col = w * 32 + ct * 16 + cl;
        float bias = bs1[col];
#pragma unroll
        for (int rt = 0; rt < 2; ++rt)
#pragma unroll
            for (int rr = 0; rr < 4; ++rr) {
                int row = row0 + rt * 16 + kg * 4 + rr;
                if (row < NN)
                    msg[(long long)row * HH + col] = (_Float16)gelu_f(acc2[rt][ct][rr] + bias);
            }
    }
}

// ---- CSR build -------------------------------------------------------------
__global__ __launch_bounds__(256)
void degree_kernel(const int* __restrict__ edges, int* __restrict__ deg)
{
    int e = blockIdx.x * 256 + threadIdx.x;
    if (e < NE) atomicAdd(&deg[edges[e]], 1);
}

__global__ __launch_bounds__(256)
void scan_partial_kernel(const int* __restrict__ deg, int* __restrict__ part)
{
    __shared__ int red[256];
    int t = threadIdx.x;
    int i = blockIdx.x * 256 + t;
    red[t] = (i < NN) ? deg[i] : 0;
    __syncthreads();
    for (int s = 128; s > 0; s >>= 1) {
        if (t < s) red[t] += red[t + s];
        __syncthreads();
    }
    if (t == 0) part[blockIdx.x] = red[0];
}

__global__ __launch_bounds__(256)
void scan_offsets_kernel(const int* __restrict__ part, int* __restrict__ boff)
{
    __shared__ int s[256];
    int t = threadIdx.x;
    s[t] = (t < SCB) ? part[t] : 0;
    __syncthreads();
    for (int off = 1; off < 256; off <<= 1) {
        int v = (t >= off) ? s[t - off] : 0;
        __syncthreads();
        s[t] += v;
        __syncthreads();
    }
    boff[t] = (t == 0) ? 0 : s[t - 1];
}

__global__ __launch_bounds__(256)
void scan_write_kernel(const int* __restrict__ deg, const int* __restrict__ boff,
                       int* __restrict__ rowptr)
{
    __shared__ int s[256];
    int t = threadIdx.x, b = blockIdx.x;
    int i = b * 256 + t;
    int v = (i < NN) ? deg[i] : 0;
    s[t] = v;
    __syncthreads();
    for (int off = 1; off < 256; off <<= 1) {
        int u = (t >= off) ? s[t - off] : 0;
        __syncthreads();
        s[t] += u;
        __syncthreads();
    }
    if (i < NN) rowptr[i] = boff[b] + (s[t] - v);
    if (b == SCB - 1 && t == 255) rowptr[NN] = boff[b] + s[255];
}

__global__ __launch_bounds__(256)
void fill_kernel(const int* __restrict__ edges, const float* __restrict__ ew,
                 const int* __restrict__ rowptr, int* __restrict__ fill,
                 int* __restrict__ colsrc, float* __restrict__ colw)
{
    int e = blockIdx.x * 256 + threadIdx.x;
    if (e >= NE) return;
    int d = edges[e];
    int pos = atomicAdd(&fill[d], 1);
    int idx = rowptr[d] + pos;
    colsrc[idx] = edges[NE + e];
    colw[idx] = ew[e];
}

// ---- gather-aggregate: 4 nodes per wave, f16x8 per lane --------------------
__global__ __launch_bounds__(256)
void gather_kernel(const int* __restrict__ rowptr, const int* __restrict__ colsrc,
                   const float* __restrict__ colw, const _Float16* __restrict__ msg,
                   _Float16* __restrict__ aggh)
{
    int gwave = (blockIdx.x * 256 + threadIdx.x) >> 6;
    int lane = threadIdx.x & 63;
    int sub = lane >> 4, l16 = lane & 15;
    int node = gwave * 4 + sub;
    if (node >= NN) return;
    int beg = rowptr[node], end = rowptr[node + 1];
    float acc[8];
#pragma unroll
    for (int q = 0; q < 8; ++q) acc[q] = 0.0f;
    for (int j = beg; j < end; ++j) {
        int src = colsrc[j];
        float w = colw[j];
        f16x8 m = *reinterpret_cast<const f16x8*>(&msg[(long long)src * HH + l16 * 8]);
#pragma unroll
        for (int q = 0; q < 8; ++q) acc[q] += (float)m[q] * w;
    }
    float inv = (end > beg) ? 1.0f / (float)(end - beg) : 0.0f;
    f16x8 o;
#pragma unroll
    for (int q = 0; q < 8; ++q) o[q] = (_Float16)(acc[q] * inv);
    *reinterpret_cast<f16x8*>(&aggh[(long long)node * HH + l16 * 8]) = o;
}

// ---- update FFN (MFMA, reg-resident B): 32 rows/block, K=256 ---------------
__global__ __launch_bounds__(256, 4)
void upd_kernel(const float* __restrict__ x, const _Float16* __restrict__ aggh,
                const _Float16* __restrict__ wt2, const float* __restrict__ bs2,
                const _Float16* __restrict__ wt3, const float* __restrict__ bs3,
                float* __restrict__ out)
{
    const int KK = DD + HH;  // 256
    __shared__ __align__(16) _Float16 smem[32 * 256];   // 16 KB, xs then ys
    const int tid = threadIdx.x;
    const int w = tid >> 6, lane = tid & 63;
    const int row0 = blockIdx.x * 32;
    const int cl = lane & 15;
    const int kg = lane >> 4;

    // layer-0 B fragments (this wave's 32 cols, all K=256)
    f16x8 b0[8][2];
#pragma unroll
    for (int kc = 0; kc < 8; ++kc)
#pragma unroll
        for (int ct = 0; ct < 2; ++ct) {
            int col = w * 32 + ct * 16 + cl;
            b0[kc][ct] = *reinterpret_cast<const f16x8*>(&wt2[(long long)col * 256 + kc * 32 + kg * 8]);
        }

    // stage concat(x f32, aggh f16) -> smem (f16, swizzled)
    for (int i = tid; i < 32 * (KK / 8); i += 256) {
        int r = i >> 5, k8 = i & 31;
        int row = row0 + r;
        f16x8 h;
        if (row < NN) {
            if (k8 < 16) {
                const float4* p = reinterpret_cast<const float4*>(&x[(long long)row * DD + k8 * 8]);
                float4 u0 = p[0], u1 = p[1];
                h[0] = (_Float16)u0.x; h[1] = (_Float16)u0.y; h[2] = (_Float16)u0.z; h[3] = (_Float16)u0.w;
                h[4] = (_Float16)u1.x; h[5] = (_Float16)u1.y; h[6] = (_Float16)u1.z; h[7] = (_Float16)u1.w;
            } else {
                h = *reinterpret_cast<const f16x8*>(&aggh[(long long)row * HH + (k8 - 16) * 8]);
            }
        } else {
#pragma unroll
            for (int q = 0; q < 8; ++q) h[q] = (_Float16)0.0f;
        }
        int slot = (r * 32 + k8) ^ (r & 7);
        *reinterpret_cast<f16x8*>(&smem[slot * 8]) = h;
    }
    __syncthreads();

    const f32x4 zero = {0.0f, 0.0f, 0.0f, 0.0f};
    f32x4 acc[2][2];
#pragma unroll
    for (int rt = 0; rt < 2; ++rt)
#pragma unroll
        for (int ct = 0; ct < 2; ++ct) acc[rt][ct] = zero;

#pragma unroll
    for (int kc = 0; kc < 8; ++kc) {
        int k8 = kc * 4 + kg;
#pragma unroll
        for (int rt = 0; rt < 2; ++rt) {
            int rA = rt * 16 + cl;
            int slot = (rA * 32 + k8) ^ (rA & 7);
            f16x8 a = *reinterpret_cast<const f16x8*>(&smem[slot * 8]);
#pragma unroll
            for (int ct = 0; ct < 2; ++ct)
                acc[rt][ct] = __builtin_amdgcn_mfma_f32_16x16x32_f16(a, b0[kc][ct], acc[rt][ct], 0, 0, 0);
        }
    }

    // layer-1 B fragments (b0 dead; loads overlap epilogue)
    f16x8 b1[4][2];
#pragma unroll
    for (int kc = 0; kc < 4; ++kc)
#pragma unroll
        for (int ct = 0; ct < 2; ++ct) {
            int col = w * 32 + ct * 16 + cl;
            b1[kc][ct] = *reinterpret_cast<const f16x8*>(&wt3[(long long)col * HH + kc * 32 + kg * 8]);
        }

    __syncthreads();   // xs reads done; smem becomes ys

#pragma unroll
    for (int ct = 0; ct < 2; ++ct) {
        int col = w * 32 + ct * 16 + cl;
        float bias = bs2[col];
#pragma unroll
        for (int rt = 0; rt < 2; ++rt)
#pragma unroll
            for (int rr = 0; rr < 4; ++rr) {
                int r = rt * 16 + kg * 4 + rr;
                float vv = gelu_f(acc[rt][ct][rr] + bias);
                int slot = (r * 16 + (col >> 3)) ^ (r & 7);
                smem[slot * 8 + (col & 7)] = (_Float16)vv;
            }
    }
    __syncthreads();

    f32x4 acc2[2][2];
#pragma unroll
    for (int rt = 0; rt < 2; ++rt)
#pragma unroll
        for (int ct = 0; ct < 2; ++ct) acc2[rt][ct] = zero;

#pragma unroll
    for (int kc = 0; kc < 4; ++kc) {
        int k8 = kc * 4 + kg;
#pragma unroll
        for (int rt = 0; rt < 2; ++rt) {
            int rA = rt * 16 + cl;
            int slot = (rA * 16 + k8) ^ (rA & 7);
            f16x8 a = *reinterpret_cast<const f16x8*>(&smem[slot * 8]);
#pragma unroll
            for (int ct = 0; ct < 2; ++ct)
                acc2[rt][ct] = __builtin_amdgcn_mfma_f32_16x16x32_f16(a, b1[kc][ct], acc2[rt][ct], 0, 0, 0);
        }
    }

#pragma unroll
    for (int ct = 0; ct < 2; ++ct) {
        int col = w * 32 + ct * 16 + cl;
        float bias = bs3[col];
#pragma unroll
        for (int rt = 0; rt < 2; ++rt)
#pragma unroll
            for (int rr = 0; rr < 4; ++rr) {
                int row = row0 + rt * 16 + kg * 4 + rr;
                if (row < NN)
                    out[(long long)row * HH + col] = gelu_f(acc2[rt][ct][rr] + bias);
            }
    }
}

extern "C" void kernel_launch(void* const* d_in, const int* in_sizes, int n_in,
                              void* d_out, int out_size, void* d_ws, size_t ws_size,
                              hipStream_t stream) {
    const float* node_repr = (const float*)d_in[0];
    const int*   edges     = (const int*)d_in[1];
    const float* ew        = (const float*)d_in[2];

    const float* prep_bn0_g = (const float*)d_in[3];
    const float* prep_bn0_b = (const float*)d_in[4];
    const float* prep_bn0_m = (const float*)d_in[5];
    const float* prep_bn0_v = (const float*)d_in[6];
    const float* prep_W0    = (const float*)d_in[7];
    const float* prep_b0    = (const float*)d_in[8];
    const float* prep_bn1_g = (const float*)d_in[9];
    const float* prep_bn1_b = (const float*)d_in[10];
    const float* prep_bn1_m = (const float*)d_in[11];
    const float* prep_bn1_v = (const float*)d_in[12];
    const float* prep_W1    = (const float*)d_in[13];
    const float* prep_b1    = (const float*)d_in[14];

    const float* upd_bn0_g = (const float*)d_in[15];
    const float* upd_bn0_b = (const float*)d_in[16];
    const float* upd_bn0_m = (const float*)d_in[17];
    const float* upd_bn0_v = (const float*)d_in[18];
    const float* upd_W0    = (const float*)d_in[19];
    const float* upd_b0    = (const float*)d_in[20];
    const float* upd_bn1_g = (const float*)d_in[21];
    const float* upd_bn1_b = (const float*)d_in[22];
    const float* upd_bn1_m = (const float*)d_in[23];
    const float* upd_bn1_v = (const float*)d_in[24];
    const float* upd_W1    = (const float*)d_in[25];
    const float* upd_b1    = (const float*)d_in[26];

    // workspace layout
    _Float16* msg  = (_Float16*)d_ws;                 // NN*HH
    _Float16* aggh = msg + (size_t)NN * HH;           // NN*HH
    _Float16* wt0  = aggh + (size_t)NN * HH;          // 128*128
    _Float16* wt1  = wt0 + 128 * 128;                 // 128*128
    _Float16* wt2  = wt1 + 128 * 128;                 // 128*256
    _Float16* wt3  = wt2 + 128 * 256;                 // 128*128
    float* bs0 = (float*)(wt3 + 128 * 128);
    float* bs1 = bs0 + 128;
    float* bs2 = bs1 + 128;
    float* bs3 = bs2 + 128;
    int* deg    = (int*)(bs3 + 128);                  // NN
    int* fill   = deg + NN;                           // NN
    int* rowptr = fill + NN;                          // NN+1
    int* part   = rowptr + NN + 1;                    // 256
    int* boff   = part + 256;                         // 256
    int* colsrc = boff + 256;                         // NE
    float* colw = (float*)(colsrc + NE);              // NE

    hipMemsetAsync(deg, 0, 2 * (size_t)NN * sizeof(int), stream);

    weights_kernel<<<128, 256, 0, stream>>>(prep_W0, prep_bn0_g, prep_bn0_b, prep_bn0_m,
                                            prep_bn0_v, prep_b0, DD, wt0, bs0);
    weights_kernel<<<128, 256, 0, stream>>>(prep_W1, prep_bn1_g, prep_bn1_b, prep_bn1_m,
                                            prep_bn1_v, prep_b1, HH, wt1, bs1);
    weights_kernel<<<128, 256, 0, stream>>>(upd_W0, upd_bn0_g, upd_bn0_b, upd_bn0_m,
                                            upd_bn0_v, upd_b0, DD + HH, wt2, bs2);
    weights_kernel<<<128, 256, 0, stream>>>(upd_W1, upd_bn1_g, upd_bn1_b, upd_bn1_m,
                                            upd_bn1_v, upd_b1, HH, wt3, bs3);

    int nblk = (NN + 31) / 32;   // 1563
    prep_kernel<<<nblk, 256, 0, stream>>>(node_repr, wt0, bs0, wt1, bs1, msg);

    int eblk = (NE + 255) / 256;
    degree_kernel<<<eblk, 256, 0, stream>>>(edges, deg);
    scan_partial_kernel<<<SCB, 256, 0, stream>>>(deg, part);
    scan_offsets_kernel<<<1, 256, 0, stream>>>(part, boff);
    scan_write_kernel<<<SCB, 256, 0, stream>>>(deg, boff, rowptr);
    fill_kernel<<<eblk, 256, 0, stream>>>(edges, ew, rowptr, fill, colsrc, colw);

    int gblk = (NN + 15) / 16;   // 16 nodes per block (4 waves x 4 nodes)
    gather_kernel<<<gblk, 256, 0, stream>>>(rowptr, colsrc, colw, msg, aggh);

    upd_kernel<<<nblk, 256, 0, stream>>>(node_repr, aggh, wt2, bs2, wt3, bs3,
                                         (float*)d_out);
}

// Round 7
// 184.243 us; speedup vs baseline: 8.8924x; 1.2415x over previous
//
#include <hip/hip_runtime.h>
#include <math.h>

#define NN 50000
#define NE 800000
#define DD 128
#define HH 128
#define BN_EPS 1e-3f
#define SCB 196   // ceil(NN/256)

typedef _Float16 f16x8 __attribute__((ext_vector_type(8)));
typedef float f32x4 __attribute__((ext_vector_type(4)));

__device__ __forceinline__ float gelu_f(float x) {
    return 0.5f * x * (1.0f + erff(x * 0.70710678118654752f));
}

// ---- fold BN into transposed f16 weights + f32 bias ------------------------
__global__ __launch_bounds__(256)
void weights_kernel(const float* __restrict__ W, const float* __restrict__ g,
                    const float* __restrict__ bb, const float* __restrict__ m,
                    const float* __restrict__ v, const float* __restrict__ bias,
                    int K, _Float16* __restrict__ wt, float* __restrict__ bs)
{
    __shared__ float red[256];
    const int n = blockIdx.x;
    const int t = threadIdx.x;
    float part = 0.0f;
    for (int k = t; k < K; k += 256) {
        float a = g[k] * rsqrtf(v[k] + BN_EPS);
        float sh = bb[k] - m[k] * a;
        float wv = W[(long long)k * HH + n];
        wt[(long long)n * K + k] = (_Float16)(wv * a);
        part += sh * wv;
    }
    red[t] = part;
    __syncthreads();
    for (int s = 128; s > 0; s >>= 1) {
        if (t < s) red[t] += red[t + s];
        __syncthreads();
    }
    if (t == 0) bs[n] = bias[n] + red[0];
}

// ---- prep FFN (MFMA, reg-resident B): 32 rows/block ------------------------
__global__ __launch_bounds__(256, 4)
void prep_kernel(const float* __restrict__ x,
                 const _Float16* __restrict__ wt0, const float* __restrict__ bs0,
                 const _Float16* __restrict__ wt1, const float* __restrict__ bs1,
                 _Float16* __restrict__ msg)
{
    __shared__ __align__(16) _Float16 smem[32 * DD];   // 8 KB, xs then ys
    const int tid = threadIdx.x;
    const int w = tid >> 6, lane = tid & 63;
    const int row0 = blockIdx.x * 32;
    const int cl = lane & 15;
    const int kg = lane >> 4;

    // layer-0 B fragments: this wave's 32 cols, all K
    f16x8 b0[4][2];
#pragma unroll
    for (int kc = 0; kc < 4; ++kc)
#pragma unroll
        for (int ct = 0; ct < 2; ++ct) {
            int col = w * 32 + ct * 16 + cl;
            b0[kc][ct] = *reinterpret_cast<const f16x8*>(&wt0[(long long)col * DD + kc * 32 + kg * 8]);
        }

    // stage x -> smem (f16, swizzled)
    for (int i = tid; i < 32 * (DD / 8); i += 256) {
        int r = i >> 4, k8 = i & 15;
        int row = row0 + r;
        f16x8 h;
        if (row < NN) {
            const float4* p = reinterpret_cast<const float4*>(&x[(long long)row * DD + k8 * 8]);
            float4 u0 = p[0], u1 = p[1];
            h[0] = (_Float16)u0.x; h[1] = (_Float16)u0.y; h[2] = (_Float16)u0.z; h[3] = (_Float16)u0.w;
            h[4] = (_Float16)u1.x; h[5] = (_Float16)u1.y; h[6] = (_Float16)u1.z; h[7] = (_Float16)u1.w;
        } else {
#pragma unroll
            for (int q = 0; q < 8; ++q) h[q] = (_Float16)0.0f;
        }
        int slot = (r * 16 + k8) ^ (r & 7);
        *reinterpret_cast<f16x8*>(&smem[slot * 8]) = h;
    }
    __syncthreads();

    const f32x4 zero = {0.0f, 0.0f, 0.0f, 0.0f};
    f32x4 acc[2][2];
#pragma unroll
    for (int rt = 0; rt < 2; ++rt)
#pragma unroll
        for (int ct = 0; ct < 2; ++ct) acc[rt][ct] = zero;

#pragma unroll
    for (int kc = 0; kc < 4; ++kc) {
        int k8 = kc * 4 + kg;
#pragma unroll
        for (int rt = 0; rt < 2; ++rt) {
            int rA = rt * 16 + cl;
            int slot = (rA * 16 + k8) ^ (rA & 7);
            f16x8 a = *reinterpret_cast<const f16x8*>(&smem[slot * 8]);
#pragma unroll
            for (int ct = 0; ct < 2; ++ct)
                acc[rt][ct] = __builtin_amdgcn_mfma_f32_16x16x32_f16(a, b0[kc][ct], acc[rt][ct], 0, 0, 0);
        }
    }

    // layer-1 B fragments (b0 now dead; latency overlaps epilogue)
    f16x8 b1[4][2];
#pragma unroll
    for (int kc = 0; kc < 4; ++kc)
#pragma unroll
        for (int ct = 0; ct < 2; ++ct) {
            int col = w * 32 + ct * 16 + cl;
            b1[kc][ct] = *reinterpret_cast<const f16x8*>(&wt1[(long long)col * HH + kc * 32 + kg * 8]);
        }

    __syncthreads();   // all xs reads done; smem becomes ys

#pragma unroll
    for (int ct = 0; ct < 2; ++ct) {
        int col = w * 32 + ct * 16 + cl;
        float bias = bs0[col];
#pragma unroll
        for (int rt = 0; rt < 2; ++rt)
#pragma unroll
            for (int rr = 0; rr < 4; ++rr) {
                int r = rt * 16 + kg * 4 + rr;
                float vv = gelu_f(acc[rt][ct][rr] + bias);
                int slot = (r * 16 + (col >> 3)) ^ (r & 7);
                smem[slot * 8 + (col & 7)] = (_Float16)vv;
            }
    }
    __syncthreads();

    f32x4 acc2[2][2];
#pragma unroll
    for (int rt = 0; rt < 2; ++rt)
#pragma unroll
        for (int ct = 0; ct < 2; ++ct) acc2[rt][ct] = zero;

#pragma unroll
    for (int kc = 0; kc < 4; ++kc) {
        int k8 = kc * 4 + kg;
#pragma unroll
        for (int rt = 0; rt < 2; ++rt) {
            int rA = rt * 16 + cl;
            int slot = (rA * 16 + k8) ^ (rA & 7);
            f16x8 a = *reinterpret_cast<const f16x8*>(&smem[slot * 8]);
#pragma unroll
            for (int ct = 0; ct < 2; ++ct)
                acc2[rt][ct] = __builtin_amdgcn_mfma_f32_16x16x32_f16(a, b1[kc][ct], acc2[rt][ct], 0, 0, 0);
        }
    }

#pragma unroll
    for (int ct = 0; ct < 2; ++ct) {
        int col = w * 32 + ct * 16 + cl;
        float bias = bs1[col];
#pragma unroll
        for (int rt = 0; rt < 2; ++rt)
#pragma unroll
            for (int rr = 0; rr < 4; ++rr) {
                int row = row0 + rt * 16 + kg * 4 + rr;
                if (row < NN)
                    msg[(long long)row * HH + col] = (_Float16)gelu_f(acc2[rt][ct][rr] + bias);
            }
    }
}

// ---- CSR build -------------------------------------------------------------
// pass 1: degree + per-edge position (coalesced pos write)
__global__ __launch_bounds__(256)
void degpos_kernel(const int* __restrict__ edges, int* __restrict__ deg,
                   int* __restrict__ pos)
{
    int e = blockIdx.x * 256 + threadIdx.x;
    if (e < NE) pos[e] = atomicAdd(&deg[edges[e]], 1);
}

__global__ __launch_bounds__(256)
void scan_partial_kernel(const int* __restrict__ deg, int* __restrict__ part)
{
    __shared__ int red[256];
    int t = threadIdx.x;
    int i = blockIdx.x * 256 + t;
    red[t] = (i < NN) ? deg[i] : 0;
    __syncthreads();
    for (int s = 128; s > 0; s >>= 1) {
        if (t < s) red[t] += red[t + s];
        __syncthreads();
    }
    if (t == 0) part[blockIdx.x] = red[0];
}

__global__ __launch_bounds__(256)
void scan_offsets_kernel(const int* __restrict__ part, int* __restrict__ boff)
{
    __shared__ int s[256];
    int t = threadIdx.x;
    s[t] = (t < SCB) ? part[t] : 0;
    __syncthreads();
    for (int off = 1; off < 256; off <<= 1) {
        int v = (t >= off) ? s[t - off] : 0;
        __syncthreads();
        s[t] += v;
        __syncthreads();
    }
    boff[t] = (t == 0) ? 0 : s[t - 1];
}

__global__ __launch_bounds__(256)
void scan_write_kernel(const int* __restrict__ deg, const int* __restrict__ boff,
                       int* __restrict__ rowptr)
{
    __shared__ int s[256];
    int t = threadIdx.x, b = blockIdx.x;
    int i = b * 256 + t;
    int v = (i < NN) ? deg[i] : 0;
    s[t] = v;
    __syncthreads();
    for (int off = 1; off < 256; off <<= 1) {
        int u = (t >= off) ? s[t - off] : 0;
        __syncthreads();
        s[t] += u;
        __syncthreads();
    }
    if (i < NN) rowptr[i] = boff[b] + (s[t] - v);
    if (b == SCB - 1 && t == 255) rowptr[NN] = boff[b] + s[255];
}

// pass 2: atomic-free fill of 8-byte {src, w_bits} records
__global__ __launch_bounds__(256)
void fill_kernel(const int* __restrict__ edges, const float* __restrict__ ew,
                 const int* __restrict__ rowptr, const int* __restrict__ pos,
                 int2* __restrict__ rec)
{
    int e = blockIdx.x * 256 + threadIdx.x;
    if (e >= NE) return;
    int d = edges[e];
    int idx = rowptr[d] + pos[e];
    int2 r;
    r.x = edges[NE + e];
    r.y = __float_as_int(ew[e]);
    rec[idx] = r;
}

// ---- gather-aggregate: 4 nodes per wave, f16x8 per lane --------------------
__global__ __launch_bounds__(256)
void gather_kernel(const int* __restrict__ rowptr, const int2* __restrict__ rec,
                   const _Float16* __restrict__ msg, _Float16* __restrict__ aggh)
{
    int gwave = (blockIdx.x * 256 + threadIdx.x) >> 6;
    int lane = threadIdx.x & 63;
    int sub = lane >> 4, l16 = lane & 15;
    int node = gwave * 4 + sub;
    if (node >= NN) return;
    int beg = rowptr[node], end = rowptr[node + 1];
    float acc[8];
#pragma unroll
    for (int q = 0; q < 8; ++q) acc[q] = 0.0f;
    for (int j = beg; j < end; ++j) {
        int2 rc = rec[j];
        int src = rc.x;
        float w = __int_as_float(rc.y);
        f16x8 m = *reinterpret_cast<const f16x8*>(&msg[(long long)src * HH + l16 * 8]);
#pragma unroll
        for (int q = 0; q < 8; ++q) acc[q] += (float)m[q] * w;
    }
    float inv = (end > beg) ? 1.0f / (float)(end - beg) : 0.0f;
    f16x8 o;
#pragma unroll
    for (int q = 0; q < 8; ++q) o[q] = (_Float16)(acc[q] * inv);
    *reinterpret_cast<f16x8*>(&aggh[(long long)node * HH + l16 * 8]) = o;
}

// ---- update FFN (MFMA, reg-resident B): 32 rows/block, K=256 ---------------
__global__ __launch_bounds__(256, 4)
void upd_kernel(const float* __restrict__ x, const _Float16* __restrict__ aggh,
                const _Float16* __restrict__ wt2, const float* __restrict__ bs2,
                const _Float16* __restrict__ wt3, const float* __restrict__ bs3,
                float* __restrict__ out)
{
    const int KK = DD + HH;  // 256
    __shared__ __align__(16) _Float16 smem[32 * 256];   // 16 KB, xs then ys
    const int tid = threadIdx.x;
    const int w = tid >> 6, lane = tid & 63;
    const int row0 = blockIdx.x * 32;
    const int cl = lane & 15;
    const int kg = lane >> 4;

    // layer-0 B fragments (this wave's 32 cols, all K=256)
    f16x8 b0[8][2];
#pragma unroll
    for (int kc = 0; kc < 8; ++kc)
#pragma unroll
        for (int ct = 0; ct < 2; ++ct) {
            int col = w * 32 + ct * 16 + cl;
            b0[kc][ct] = *reinterpret_cast<const f16x8*>(&wt2[(long long)col * 256 + kc * 32 + kg * 8]);
        }

    // stage concat(x f32, aggh f16) -> smem (f16, swizzled)
    for (int i = tid; i < 32 * (KK / 8); i += 256) {
        int r = i >> 5, k8 = i & 31;
        int row = row0 + r;
        f16x8 h;
        if (row < NN) {
            if (k8 < 16) {
                const float4* p = reinterpret_cast<const float4*>(&x[(long long)row * DD + k8 * 8]);
                float4 u0 = p[0], u1 = p[1];
                h[0] = (_Float16)u0.x; h[1] = (_Float16)u0.y; h[2] = (_Float16)u0.z; h[3] = (_Float16)u0.w;
                h[4] = (_Float16)u1.x; h[5] = (_Float16)u1.y; h[6] = (_Float16)u1.z; h[7] = (_Float16)u1.w;
            } else {
                h = *reinterpret_cast<const f16x8*>(&aggh[(long long)row * HH + (k8 - 16) * 8]);
            }
        } else {
#pragma unroll
            for (int q = 0; q < 8; ++q) h[q] = (_Float16)0.0f;
        }
        int slot = (r * 32 + k8) ^ (r & 7);
        *reinterpret_cast<f16x8*>(&smem[slot * 8]) = h;
    }
    __syncthreads();

    const f32x4 zero = {0.0f, 0.0f, 0.0f, 0.0f};
    f32x4 acc[2][2];
#pragma unroll
    for (int rt = 0; rt < 2; ++rt)
#pragma unroll
        for (int ct = 0; ct < 2; ++ct) acc[rt][ct] = zero;

#pragma unroll
    for (int kc = 0; kc < 8; ++kc) {
        int k8 = kc * 4 + kg;
#pragma unroll
        for (int rt = 0; rt < 2; ++rt) {
            int rA = rt * 16 + cl;
            int slot = (rA * 32 + k8) ^ (rA & 7);
            f16x8 a = *reinterpret_cast<const f16x8*>(&smem[slot * 8]);
#pragma unroll
            for (int ct = 0; ct < 2; ++ct)
                acc[rt][ct] = __builtin_amdgcn_mfma_f32_16x16x32_f16(a, b0[kc][ct], acc[rt][ct], 0, 0, 0);
        }
    }

    // layer-1 B fragments (b0 dead; loads overlap epilogue)
    f16x8 b1[4][2];
#pragma unroll
    for (int kc = 0; kc < 4; ++kc)
#pragma unroll
        for (int ct = 0; ct < 2; ++ct) {
            int col = w * 32 + ct * 16 + cl;
            b1[kc][ct] = *reinterpret_cast<const f16x8*>(&wt3[(long long)col * HH + kc * 32 + kg * 8]);
        }

    __syncthreads();   // xs reads done; smem becomes ys

#pragma unroll
    for (int ct = 0; ct < 2; ++ct) {
        int col = w * 32 + ct * 16 + cl;
        float bias = bs2[col];
#pragma unroll
        for (int rt = 0; rt < 2; ++rt)
#pragma unroll
            for (int rr = 0; rr < 4; ++rr) {
                int r = rt * 16 + kg * 4 + rr;
                float vv = gelu_f(acc[rt][ct][rr] + bias);
                int slot = (r * 16 + (col >> 3)) ^ (r & 7);
                smem[slot * 8 + (col & 7)] = (_Float16)vv;
            }
    }
    __syncthreads();

    f32x4 acc2[2][2];
#pragma unroll
    for (int rt = 0; rt < 2; ++rt)
#pragma unroll
        for (int ct = 0; ct < 2; ++ct) acc2[rt][ct] = zero;

#pragma unroll
    for (int kc = 0; kc < 4; ++kc) {
        int k8 = kc * 4 + kg;
#pragma unroll
        for (int rt = 0; rt < 2; ++rt) {
            int rA = rt * 16 + cl;
            int slot = (rA * 16 + k8) ^ (rA & 7);
            f16x8 a = *reinterpret_cast<const f16x8*>(&smem[slot * 8]);
#pragma unroll
            for (int ct = 0; ct < 2; ++ct)
                acc2[rt][ct] = __builtin_amdgcn_mfma_f32_16x16x32_f16(a, b1[kc][ct], acc2[rt][ct], 0, 0, 0);
        }
    }

#pragma unroll
    for (int ct = 0; ct < 2; ++ct) {
        int col = w * 32 + ct * 16 + cl;
        float bias = bs3[col];
#pragma unroll
        for (int rt = 0; rt < 2; ++rt)
#pragma unroll
            for (int rr = 0; rr < 4; ++rr) {
                int row = row0 + rt * 16 + kg * 4 + rr;
                if (row < NN)
                    out[(long long)row * HH + col] = gelu_f(acc2[rt][ct][rr] + bias);
            }
    }
}

extern "C" void kernel_launch(void* const* d_in, const int* in_sizes, int n_in,
                              void* d_out, int out_size, void* d_ws, size_t ws_size,
                              hipStream_t stream) {
    const float* node_repr = (const float*)d_in[0];
    const int*   edges     = (const int*)d_in[1];
    const float* ew        = (const float*)d_in[2];

    const float* prep_bn0_g = (const float*)d_in[3];
    const float* prep_bn0_b = (const float*)d_in[4];
    const float* prep_bn0_m = (const float*)d_in[5];
    const float* prep_bn0_v = (const float*)d_in[6];
    const float* prep_W0    = (const float*)d_in[7];
    const float* prep_b0    = (const float*)d_in[8];
    const float* prep_bn1_g = (const float*)d_in[9];
    const float* prep_bn1_b = (const float*)d_in[10];
    const float* prep_bn1_m = (const float*)d_in[11];
    const float* prep_bn1_v = (const float*)d_in[12];
    const float* prep_W1    = (const float*)d_in[13];
    const float* prep_b1    = (const float*)d_in[14];

    const float* upd_bn0_g = (const float*)d_in[15];
    const float* upd_bn0_b = (const float*)d_in[16];
    const float* upd_bn0_m = (const float*)d_in[17];
    const float* upd_bn0_v = (const float*)d_in[18];
    const float* upd_W0    = (const float*)d_in[19];
    const float* upd_b0    = (const float*)d_in[20];
    const float* upd_bn1_g = (const float*)d_in[21];
    const float* upd_bn1_b = (const float*)d_in[22];
    const float* upd_bn1_m = (const float*)d_in[23];
    const float* upd_bn1_v = (const float*)d_in[24];
    const float* upd_W1    = (const float*)d_in[25];
    const float* upd_b1    = (const float*)d_in[26];

    // workspace layout
    _Float16* msg  = (_Float16*)d_ws;                 // NN*HH
    _Float16* aggh = msg + (size_t)NN * HH;           // NN*HH
    _Float16* wt0  = aggh + (size_t)NN * HH;          // 128*128
    _Float16* wt1  = wt0 + 128 * 128;                 // 128*128
    _Float16* wt2  = wt1 + 128 * 128;                 // 128*256
    _Float16* wt3  = wt2 + 128 * 256;                 // 128*128
    float* bs0 = (float*)(wt3 + 128 * 128);
    float* bs1 = bs0 + 128;
    float* bs2 = bs1 + 128;
    float* bs3 = bs2 + 128;
    int* deg    = (int*)(bs3 + 128);                  // NN
    int* rowptr = deg + NN;                           // NN+1
    int* part   = rowptr + NN + 1;                    // 256
    int* boff   = part + 256;                         // 256
    int* pos    = boff + 256;                         // NE
    int2* rec   = (int2*)(pos + NE);                  // NE (8B each)

    hipMemsetAsync(deg, 0, (size_t)NN * sizeof(int), stream);

    weights_kernel<<<128, 256, 0, stream>>>(prep_W0, prep_bn0_g, prep_bn0_b, prep_bn0_m,
                                            prep_bn0_v, prep_b0, DD, wt0, bs0);
    weights_kernel<<<128, 256, 0, stream>>>(prep_W1, prep_bn1_g, prep_bn1_b, prep_bn1_m,
                                            prep_bn1_v, prep_b1, HH, wt1, bs1);
    weights_kernel<<<128, 256, 0, stream>>>(upd_W0, upd_bn0_g, upd_bn0_b, upd_bn0_m,
                                            upd_bn0_v, upd_b0, DD + HH, wt2, bs2);
    weights_kernel<<<128, 256, 0, stream>>>(upd_W1, upd_bn1_g, upd_bn1_b, upd_bn1_m,
                                            upd_bn1_v, upd_b1, HH, wt3, bs3);

    int nblk = (NN + 31) / 32;   // 1563
    prep_kernel<<<nblk, 256, 0, stream>>>(node_repr, wt0, bs0, wt1, bs1, msg);

    int eblk = (NE + 255) / 256;
    degpos_kernel<<<eblk, 256, 0, stream>>>(edges, deg, pos);
    scan_partial_kernel<<<SCB, 256, 0, stream>>>(deg, part);
    scan_offsets_kernel<<<1, 256, 0, stream>>>(part, boff);
    scan_write_kernel<<<SCB, 256, 0, stream>>>(deg, boff, rowptr);
    fill_kernel<<<eblk, 256, 0, stream>>>(edges, ew, rowptr, pos, rec);

    int gblk = (NN + 15) / 16;   // 16 nodes per block (4 waves x 4 nodes)
    gather_kernel<<<gblk, 256, 0, stream>>>(rowptr, rec, msg, aggh);

    upd_kernel<<<nblk, 256, 0, stream>>>(node_repr, aggh, wt2, bs2, wt3, bs3,
                                         (float*)d_out);
}